// Round 17
// baseline (322.944 us; speedup 1.0000x reference)
//
#include <hip/hip_runtime.h>
#include <cstdint>
#include <cstddef>

// ---------------- constants ----------------
constexpr int T_SEQ = 4096;
constexpr int NH    = 16;
constexpr int HD    = 128;
constexpr int DIM   = 2048;
constexpr int HDIM  = 2048;   // NH*HD

typedef __attribute__((ext_vector_type(8)))  short  short8;
typedef __attribute__((ext_vector_type(4)))  float  f32x4;
typedef __attribute__((ext_vector_type(16))) float  f32x16;
typedef __attribute__((ext_vector_type(8)))  unsigned short u16x8;
typedef __attribute__((ext_vector_type(4)))  unsigned short u16x4;
typedef __attribute__((ext_vector_type(4)))  unsigned uint4v;
typedef __attribute__((ext_vector_type(2)))  int int2v;

__device__ __forceinline__ unsigned short f2bf(float f) {
  unsigned u = __float_as_uint(f);
  return (unsigned short)((u + 0x7FFFu + ((u >> 16) & 1u)) >> 16);  // RNE
}
__device__ __forceinline__ float bf2f(unsigned short h) {
  return __uint_as_float(((unsigned)h) << 16);
}
__device__ __forceinline__ void gload_lds16(const void* g, void* l) {
  __builtin_amdgcn_global_load_lds((const __attribute__((address_space(1))) void*)g,
                                   (__attribute__((address_space(3))) void*)l, 16, 0, 0);
}
__device__ __forceinline__ int2v plswap(int a, int b) {
  return __builtin_amdgcn_permlane32_swap(a, b, false, false);
}
__device__ __forceinline__ void bar() {           // raw barrier: no implicit vmcnt(0)
  asm volatile("" ::: "memory");
  __builtin_amdgcn_s_barrier();
  asm volatile("" ::: "memory");
}
#define VMCNT(n) asm volatile("s_waitcnt vmcnt(" #n ")" ::: "memory")
#define LGKM0()  asm volatile("s_waitcnt lgkmcnt(0)" ::: "memory")

// ---------------- fused prep: 3x fp32->bf16 convert + RoPE tables, one launch ----------
__global__ __launch_bounds__(256) void prep_all(const float* __restrict__ x,
                                                const float* __restrict__ qkv_w,
                                                const float* __restrict__ proj_w,
                                                unsigned short* __restrict__ xb,
                                                unsigned short* __restrict__ wqb,
                                                unsigned short* __restrict__ pwb,
                                                float* __restrict__ cosT,
                                                float* __restrict__ sinT) {
  constexpr int N1 = T_SEQ * DIM / 4;              // 2,097,152
  constexpr int N2 = N1 + 3 * HDIM * DIM / 4;      // +3,145,728
  constexpr int N3 = N2 + DIM * HDIM / 4;          // +1,048,576
  int gid = blockIdx.x * 256 + threadIdx.x;
  const float* src; unsigned short* dst; int i4;
  if (gid < N1)      { src = x;      dst = xb;  i4 = gid; }
  else if (gid < N2) { src = qkv_w;  dst = wqb; i4 = gid - N1; }
  else if (gid < N3) { src = proj_w; dst = pwb; i4 = gid - N2; }
  else {
    int idx = gid - N3;                            // T_SEQ*64 entries
    int t = idx >> 6, i = idx & 63;
    float ang = (i < 32) ? exp2f(-10.0f * (float)i / 31.0f) : 0.0f;  // (1/1024)^(i/31)
    float th = (float)t * ang;
    cosT[idx] = cosf(th);
    sinT[idx] = sinf(th);
    return;
  }
  float4 v = ((const float4*)src)[i4];
  u16x4 o; o.x = f2bf(v.x); o.y = f2bf(v.y); o.z = f2bf(v.z); o.w = f2bf(v.w);
  ((u16x4*)dst)[i4] = o;
}

// ---------------- QKV GEMM: BK=32, 2-buffer 48KB LDS -> 2 blocks/CU, 4 waves/SIMD ----
// gemm256 (144KB LDS) was 1 block/CU = 2 waves/SIMD -> latency-bound staging.
// BK=32 halves the tile so two blocks co-reside. Per K-tile:
//   vmcnt(3) [tile t's 3 loads drained; t+1's stay in flight]; bar [all waves' t landed];
//   8x ds_read; lgkmcnt(0); bar [all waves' reads retired]; re-stage buf for t+2; 16 MFMA.
// Swizzle (64B rows, 4x16B slots): write slot_src=(lane&3)^((lane>>3)&3) keyed on
// (global_row>>1)&3; read slot = lr^((lc>>1)&3) — same key, both-sides consistent.
__global__ __launch_bounds__(512) void gemmQ(const unsigned short* __restrict__ A,
                                             const unsigned short* __restrict__ B,
                                             unsigned short* __restrict__ outb) {
  __shared__ __align__(16) char SM[2 * 24576];   // 48KB: 2 x [A 8KB | B 16KB]
  const int tid = threadIdx.x, w = tid >> 6, lane = tid & 63;
  const int wm = w >> 2, wn = w & 3;
  const int lr = lane >> 4, lc = lane & 15;
  const int cpx = gridDim.x >> 3;
  const int idx = (blockIdx.x & 7) * cpx + (blockIdx.x >> 3);
  const int m0 = (idx & 31) * 128, n0 = (idx >> 5) * 256;

  const int srow = lane >> 2;                         // row within 16-row chunk
  const int scol = ((lane & 3) ^ ((lane >> 3) & 3)) * 8;  // pre-swizzled source col

  auto stage = [&](int buf, int t) {                  // 3 loads/thread
    char* Abase = SM + buf * 24576;
    char* Bbase = Abase + 8192;
    gload_lds16(A + (size_t)(m0 + w * 16 + srow) * DIM + t * 32 + scol, Abase + w * 1024);
#pragma unroll
    for (int i = 0; i < 2; i++) {
      int c = w + i * 8;
      gload_lds16(B + (size_t)(n0 + c * 16 + srow) * DIM + t * 32 + scol, Bbase + c * 1024);
    }
  };

  f32x4 acc[4][4] = {};
  constexpr int NT = DIM / 32;                        // 64

  stage(0, 0);
  stage(1, 1);

  const int sl = (lr ^ ((lc >> 1) & 3)) * 16;         // read slot (row-base mult of 16)

#pragma unroll 1
  for (int t = 0; t < NT; t++) {
    const int buf = t & 1;
    const char* Ab = SM + buf * 24576;
    const char* Bb = Ab + 8192;

    if (t < NT - 1) { VMCNT(3); } else { VMCNT(0); }  // own t-loads drained
    bar();                                            // all waves' t-stages landed

    short8 a[4], b[4];
#pragma unroll
    for (int mi = 0; mi < 4; mi++)
      a[mi] = *(const short8*)(Ab + (wm * 64 + mi * 16 + lc) * 64 + sl);
#pragma unroll
    for (int ni = 0; ni < 4; ni++)
      b[ni] = *(const short8*)(Bb + (wn * 64 + ni * 16 + lc) * 64 + sl);
    LGKM0();                                          // own reads retired
    bar();                                            // all waves' reads retired
    if (t + 2 < NT) stage(buf, t + 2);                // safe to overwrite buf

    __builtin_amdgcn_s_setprio(1);
#pragma unroll
    for (int mi = 0; mi < 4; mi++)
#pragma unroll
      for (int ni = 0; ni < 4; ni++)
        acc[mi][ni] = __builtin_amdgcn_mfma_f32_16x16x32_bf16(a[mi], b[ni], acc[mi][ni], 0, 0, 0);
    __builtin_amdgcn_s_setprio(0);
  }

  // epilogue: write bf16 into qkv layout [c][h][t][d]
#pragma unroll
  for (int mi = 0; mi < 4; mi++)
#pragma unroll
    for (int ni = 0; ni < 4; ni++)
#pragma unroll
      for (int r = 0; r < 4; r++) {
        int t = m0 + wm * 64 + mi * 16 + lr * 4 + r;
        int n = n0 + wn * 64 + ni * 16 + lc;
        float v = acc[mi][ni][r];
        int cc = n >> 11, e = n & 2047, h = e >> 7, d = e & 127;
        outb[(((size_t)cc * NH + h) * T_SEQ + t) * HD + d] = f2bf(v);
      }
}

// ---------------- proj GEMM: BM=128,BN=256,BK=64, 3-buffer (R16 version, 36us) --------
__global__ __launch_bounds__(512) void gemm256(const unsigned short* __restrict__ A,
                                               const unsigned short* __restrict__ B,
                                               int K, float* __restrict__ outf, int N) {
  __shared__ __align__(16) char SM[3 * 49152];   // 144KB: 3 x [A 16KB | B 32KB]
  const int tid = threadIdx.x, w = tid >> 6, lane = tid & 63;
  const int wm = w >> 2, wn = w & 3;
  const int lr = lane >> 4, lc = lane & 15, lc7 = lc & 7;
  const int cpx = gridDim.x >> 3;
  const int idx = (blockIdx.x & 7) * cpx + (blockIdx.x >> 3);
  const int m0 = (idx & 31) * 128, n0 = (idx >> 5) * 256;

  const int arow = lane >> 3;
  const int xcol = ((lane & 7) ^ ((lane >> 3) & 7)) * 8;  // pre-swizzled source col

  auto stageA = [&](int buf, int t) {
    char* base = SM + buf * 49152;
#pragma unroll
    for (int i = 0; i < 2; i++) {
      int c = w + i * 8;
      gload_lds16(A + (size_t)(m0 + c * 8 + arow) * K + t * 64 + xcol, base + c * 1024);
    }
  };
  auto stageB0 = [&](int buf, int t) {
    char* base = SM + buf * 49152 + 16384;
    gload_lds16(B + (size_t)(n0 + w * 8 + arow) * K + t * 64 + xcol, base + w * 1024);
  };
  auto stageB1 = [&](int buf, int t) {
    char* base = SM + buf * 49152 + 16384;
#pragma unroll
    for (int i = 1; i < 4; i++) {
      int c = w + i * 8;
      gload_lds16(B + (size_t)(n0 + c * 8 + arow) * K + t * 64 + xcol, base + c * 1024);
    }
  };

  f32x4 acc[4][4] = {};
  const int NT = K >> 6;

  stageA(0, 0); stageB0(0, 0); stageB1(0, 0);
  stageA(1, 1); stageB0(1, 1); stageB1(1, 1);
  VMCNT(6);
  bar();

#pragma unroll 1
  for (int t = 0; t < NT; t++) {
    const int c = t % 3, s = (t + 2) % 3;
    const bool st = (t + 2) < NT;
    const char* Ab = SM + c * 49152;
    const char* Bb = Ab + 16384;

    short8 a[4], b[4];
#pragma unroll
    for (int mi = 0; mi < 4; mi++)
      a[mi] = *(const short8*)(Ab + (wm * 64 + mi * 16 + lc) * 128 + ((0 + lr) ^ lc7) * 16);
#pragma unroll
    for (int ni = 0; ni < 4; ni++)
      b[ni] = *(const short8*)(Bb + (wn * 64 + ni * 16 + lc) * 128 + ((0 + lr) ^ lc7) * 16);
    if (st) { stageA(s, t + 2); stageB0(s, t + 2); }
    __builtin_amdgcn_s_setprio(1);
#pragma unroll
    for (int mi = 0; mi < 4; mi++)
#pragma unroll
      for (int ni = 0; ni < 4; ni++)
        acc[mi][ni] = __builtin_amdgcn_mfma_f32_16x16x32_bf16(a[mi], b[ni], acc[mi][ni], 0, 0, 0);
    __builtin_amdgcn_s_setprio(0);

#pragma unroll
    for (int mi = 0; mi < 4; mi++)
      a[mi] = *(const short8*)(Ab + (wm * 64 + mi * 16 + lc) * 128 + ((4 + lr) ^ lc7) * 16);
#pragma unroll
    for (int ni = 0; ni < 4; ni++)
      b[ni] = *(const short8*)(Bb + (wn * 64 + ni * 16 + lc) * 128 + ((4 + lr) ^ lc7) * 16);
    if (st) stageB1(s, t + 2);
    if (st) { VMCNT(6); } else { VMCNT(0); }
    bar();
    __builtin_amdgcn_s_setprio(1);
#pragma unroll
    for (int mi = 0; mi < 4; mi++)
#pragma unroll
      for (int ni = 0; ni < 4; ni++)
        acc[mi][ni] = __builtin_amdgcn_mfma_f32_16x16x32_bf16(a[mi], b[ni], acc[mi][ni], 0, 0, 0);
    __builtin_amdgcn_s_setprio(0);
    bar();
  }

#pragma unroll
  for (int mi = 0; mi < 4; mi++)
#pragma unroll
    for (int ni = 0; ni < 4; ni++)
#pragma unroll
      for (int r = 0; r < 4; r++) {
        int t = m0 + wm * 64 + mi * 16 + lr * 4 + r;
        int n = n0 + wn * 64 + ni * 16 + lc;
        outf[(size_t)t * N + n] = acc[mi][ni][r];
      }
}

// ---------------- RMSNorm + RoPE (in-place on q,k; layout [c][h][t][d]) ----------------
__global__ __launch_bounds__(256) void norm_rope(unsigned short* __restrict__ qkvb,
                                                 const float* __restrict__ cosT,
                                                 const float* __restrict__ sinT) {
  const int tid = threadIdx.x;
  const int li = tid & 15;                          // position within row (8 elems each)
  const int row = blockIdx.x * 16 + (tid >> 4);     // row over [c][h][t]
  const int t = row & (T_SEQ - 1);
  unsigned short* rp = qkvb + (size_t)row * HD + li * 8;
  u16x8 raw = *(const u16x8*)rp;

  float v[8]; float ss = 0.0f;
#pragma unroll
  for (int j = 0; j < 8; j++) { v[j] = bf2f(raw[j]); ss += v[j] * v[j]; }
#pragma unroll
  for (int off = 1; off < 16; off <<= 1) ss += __shfl_xor(ss, off, 16);
  float rs = rsqrtf(ss * (1.0f / 128.0f) + 1e-6f);
  if (row < NH * T_SEQ) rs *= 0.088388347648318447f * 1.44269504f;  // q rows only

  uint4v rw = __builtin_bit_cast(uint4v, raw);
  uint4v pwv;
  pwv.x = (unsigned)__shfl_xor((int)rw.x, 8, 16);
  pwv.y = (unsigned)__shfl_xor((int)rw.y, 8, 16);
  pwv.z = (unsigned)__shfl_xor((int)rw.z, 8, 16);
  pwv.w = (unsigned)__shfl_xor((int)rw.w, 8, 16);
  u16x8 praw = __builtin_bit_cast(u16x8, pwv);
  float pv[8];
#pragma unroll
  for (int j = 0; j < 8; j++) pv[j] = bf2f(praw[j]);

  const int e0 = (li & 7) * 8;
  const bool hi8 = li >= 8;
  float4 c0 = *(const float4*)(cosT + t * 64 + e0);
  float4 c1 = *(const float4*)(cosT + t * 64 + e0 + 4);
  float4 s0 = *(const float4*)(sinT + t * 64 + e0);
  float4 s1 = *(const float4*)(sinT + t * 64 + e0 + 4);
  float cc[8] = {c0.x, c0.y, c0.z, c0.w, c1.x, c1.y, c1.z, c1.w};
  float sn[8] = {s0.x, s0.y, s0.z, s0.w, s1.x, s1.y, s1.z, s1.w};

  u16x8 o;
#pragma unroll
  for (int j = 0; j < 8; j++) {
    float x1 = hi8 ? pv[j] : v[j];
    float x2 = hi8 ? v[j] : pv[j];
    float r = hi8 ? (-x1 * sn[j] + x2 * cc[j]) : (x1 * cc[j] + x2 * sn[j]);
    o[j] = f2bf(r * rs);
  }
  *(u16x8*)rp = o;
}

// ---------------- v' = l0*v + l1*ve, transposed to v_t[h][d][t] ----------------
__global__ __launch_bounds__(256) void vmix_transpose(const unsigned short* __restrict__ vb,
                                                      const float* __restrict__ ve,
                                                      const float* __restrict__ lam,
                                                      unsigned short* __restrict__ vt) {
  __shared__ float tile[64][65];
  const int h = blockIdx.z, t0 = blockIdx.x * 64, d0 = blockIdx.y * 64;
  const float l0 = lam[0], l1 = lam[1];
  const int tid = threadIdx.x;
  const int tl = tid >> 4, dl4 = (tid & 15) * 4;
#pragma unroll
  for (int i = 0; i < 4; i++) {
    int t_local = tl + i * 16;
    int t = t0 + t_local;
    const unsigned short* vp = vb + ((size_t)h * T_SEQ + t) * HD + d0 + dl4;
    const float* vep = ve + (size_t)t * HDIM + h * HD + d0 + dl4;
    u16x4 vv = *(const u16x4*)vp;
    float4 vef = *(const float4*)vep;
    tile[t_local][dl4 + 0] = l0 * bf2f(vv.x) + l1 * vef.x;
    tile[t_local][dl4 + 1] = l0 * bf2f(vv.y) + l1 * vef.y;
    tile[t_local][dl4 + 2] = l0 * bf2f(vv.z) + l1 * vef.z;
    tile[t_local][dl4 + 3] = l0 * bf2f(vv.w) + l1 * vef.w;
  }
  __syncthreads();
#pragma unroll
  for (int i = 0; i < 2; i++) {
    int idx = tid + i * 256;
    int d_local = idx >> 3, tloc = (idx & 7) * 8;
    u16x8 o;
#pragma unroll
    for (int j = 0; j < 8; j++) o[j] = f2bf(tile[tloc + j][d_local]);
    *(u16x8*)(vt + ((size_t)h * HD + d0 + d_local) * T_SEQ + t0 + tloc) = o;
  }
}

// ---------------- flash attention (causal), swapped-operand 32x32x16 ----------------
// R15/R16 version (143us): fixed-max softmax (FM=16.5), K-row permutation (lane-local
// PV), kv-parity group split with drift barriers.
__global__ __launch_bounds__(512)
__attribute__((amdgpu_waves_per_eu(2, 2)))
void attn_fwd(const unsigned short* __restrict__ qb,
              const unsigned short* __restrict__ kb,
              const unsigned short* __restrict__ vt,
              unsigned short* __restrict__ ao) {
  __shared__ __align__(16) char SMEM[131072];   // [group][ K 2x16KB | V 2x16KB ]
  __shared__ int gctr[2];                       // group-barrier monotonic counters
  const int bid = blockIdx.x;
  const int h  = (bid & 7) + ((bid >> 7) << 3);  // XCD swizzle: head h on XCD h%8
  const int pr = (bid >> 3) & 15;
  const int tid = threadIdx.x, w = tid >> 6, lane = tid & 63;
  const int g = w >> 2, wq = w & 3;
  const int l31 = lane & 31, hi = lane >> 5, r7 = l31 & 7;
  const unsigned short* qh = qb + (size_t)h * T_SEQ * HD;
  const unsigned short* kh = kb + (size_t)h * T_SEQ * HD;
  const unsigned short* vh = vt + (size_t)h * HD * T_SEQ;

  if (tid < 2) gctr[tid] = 0;
  __syncthreads();
  int bcnt = 0;
  auto GBAR = [&]() {   // group-local barrier: 4 waves of group g
    asm volatile("s_waitcnt lgkmcnt(0)" ::: "memory");
    ++bcnt;
    if (lane == 0)
      __hip_atomic_fetch_add(&gctr[g], 1, __ATOMIC_RELEASE, __HIP_MEMORY_SCOPE_WORKGROUP);
    while (__hip_atomic_load(&gctr[g], __ATOMIC_ACQUIRE, __HIP_MEMORY_SCOPE_WORKGROUP) < 4 * bcnt)
      __builtin_amdgcn_s_sleep(1);
  };

  char* Kbase = SMEM + g * 65536;
  char* Vbase = SMEM + g * 65536 + 32768;

  const int kcrow = lane >> 4, kcol16 = lane & 15;   // K staging: 4 rows / 1KB chunk
  const int vcrow = lane >> 3, vslot0 = lane & 7;    // V staging: 8 rows / 1KB chunk

  auto STAGE = [&](int buf, int t) {                 // t = global kv tile index
#pragma unroll
    for (int i = 0; i < 4; i++) {
      int krow = (wq * 4 + i) * 4 + kcrow;           // LDS position
      int ksrc = (krow & ~12) | ((krow & 4) << 1) | ((krow & 8) >> 1);  // sigma: b2<->b3
      int kcol = (kcol16 ^ (krow & 7)) * 8;          // pre-swizzled source (rule #21)
      gload_lds16(kh + (size_t)(t * 64 + ksrc) * HD + kcol,
                  Kbase + buf * 16384 + (wq * 4 + i) * 1024);
      int vrow = (wq * 4 + i) * 8 + vcrow;
      int vcol = (vslot0 ^ (vrow & 7)) * 8;
      gload_lds16(vh + (size_t)vrow * T_SEQ + t * 64 + vcol,
                  Vbase + buf * 16384 + (wq * 4 + i) * 1024);
    }
  };

  const float FM = 16.5f;   // fixed softmax max (exp2 domain), > score bound 16.46

#pragma unroll 1
  for (int which = 0; which < 2; ++which) {
    const int qt = which ? pr : (31 - pr);     // heavy tile first
    const int ng = qt + 1;                     // tiles for THIS group (parity g)
    const int q_row = qt * 128 + wq * 32 + l31;

    short8 qf[8];                              // B-frag: Q[q_row][16dk + 8hi + 0..7]
#pragma unroll
    for (int dk = 0; dk < 8; dk++)
      qf[dk] = *(const short8*)(qh + (size_t)q_row * HD + dk * 16 + hi * 8);

    f32x16 accO[4] = {};                       // O^T: col=q, rows d (4 tiles of 32)
    float l_r = 0.0f;

    __syncthreads();                           // prev combine reads done (cross-group)
    STAGE(0, g);

#pragma unroll 1
    for (int it = 0; it < ng; it++) {
      const int t = 2 * it + g;                // this group's kv tile
      const int cur = it & 1;
      asm volatile("s_waitcnt vmcnt(0)" ::: "memory");  // own stage(cur) landed
      GBAR();                                           // group's stage(cur) landed
      if (it + 1 < ng) STAGE(cur ^ 1, t + 2);           // prefetch under compute

      // ---- S^T = K Q^T : 2 kv-subtiles x 8 d-steps (scores pre-scaled via Q) ----
      f32x16 accS0 = {}, accS1 = {};
      const char* Kb = Kbase + cur * 16384 + l31 * 256;
      __builtin_amdgcn_s_setprio(1);
#pragma unroll
      for (int dk = 0; dk < 8; dk++) {
        int sl = ((2 * dk + hi) ^ r7) * 16;
        short8 k0 = *(const short8*)(Kb + sl);
        short8 k1 = *(const short8*)(Kb + 32 * 256 + sl);
        accS0 = __builtin_amdgcn_mfma_f32_32x32x16_bf16(k0, qf[dk], accS0, 0, 0, 0);
        accS1 = __builtin_amdgcn_mfma_f32_32x32x16_bf16(k1, qf[dk], accS1, 0, 0, 0);
      }
      __builtin_amdgcn_s_setprio(0);

      // ---- causal mask + exp2(s - FM); permuted layout: kv = 64t+(r&7)+8hi+16(r>>3) ----
      float p[32];
      const bool need_mask = (t * 64 + 63) > (qt * 128 + wq * 32);
      if (need_mask) {
#pragma unroll
        for (int r = 0; r < 16; r++) {
          int kv0 = t * 64 + (r & 7) + 8 * hi + 16 * (r >> 3);
          p[r]      = (kv0      > q_row) ? 0.0f : exp2f(accS0[r] - FM);
          p[16 + r] = (kv0 + 32 > q_row) ? 0.0f : exp2f(accS1[r] - FM);
        }
      } else {
#pragma unroll
        for (int r = 0; r < 16; r++) {
          p[r]      = exp2f(accS0[r] - FM);
          p[16 + r] = exp2f(accS1[r] - FM);
        }
      }

      // ---- row sum (partner holds complementary kv set; one cross-half swap) ----
      float s16[16];
#pragma unroll
      for (int i = 0; i < 16; i++) s16[i] = p[i] + p[i + 16];
#pragma unroll
      for (int st = 8; st >= 1; st >>= 1)
#pragma unroll
        for (int i = 0; i < st; i++) s16[i] += s16[i + st];
      int2v sr_ = plswap(__float_as_int(s16[0]), __float_as_int(s16[0]));
      l_r += s16[0] + __int_as_float(hi ? sr_.x : sr_.y);

      // ---- PV: O^T += V^T P^T ; pb[ks] = p[8ks..8ks+7] (lane-local, no exchange) ----
      const char* Vb = Vbase + cur * 16384 + l31 * 128;
#pragma unroll
      for (int ks = 0; ks < 4; ks++) {
        uint4v pw;
#pragma unroll
        for (int w2 = 0; w2 < 4; w2++) {
          unsigned pk_;
          asm("v_cvt_pk_bf16_f32 %0, %1, %2"
              : "=v"(pk_) : "v"(p[8 * ks + 2 * w2]), "v"(p[8 * ks + 2 * w2 + 1]));
          pw[w2] = pk_;
        }
        short8 pb = __builtin_bit_cast(short8, pw);
        int sl = ((2 * ks + hi) ^ r7) * 16;
        __builtin_amdgcn_s_setprio(1);
#pragma unroll
        for (int dt = 0; dt < 4; dt++) {
          short8 vf = *(const short8*)(Vb + dt * 32 * 128 + sl);
          accO[dt] = __builtin_amdgcn_mfma_f32_32x32x16_bf16(vf, pb, accO[dt], 0, 0, 0);
        }
        __builtin_amdgcn_s_setprio(0);
      }
    }

    // ---- combine even/odd partials (fixed max -> merge is a plain sum) ----
    __syncthreads();                                  // all compute done (cross-group)
    float* SM_acc = (float*)(SMEM + 65536);           // odd group's staging (dead now)
    float* SM_l   = (float*)SMEM;                     // even group's staging (dead now)
    const int q_local = wq * 32 + l31;
    if (g == 1) {
#pragma unroll
      for (int dt = 0; dt < 4; dt++)
#pragma unroll
        for (int r = 0; r < 16; r++) {
          int d = 32 * dt + (r & 3) + 8 * (r >> 2) + 4 * hi;
          SM_acc[q_local * 128 + (d ^ l31)] = accO[dt][r];   // word-swz: conflict-free
        }
      if (hi == 0) SM_l[q_local] = l_r;
    }
    __syncthreads();                                  // partials visible
    if (g == 0) {
      float lo = SM_l[q_local];
      float inv = 1.0f / (l_r + lo);                  // l_r > 0 (diagonal in even group)
#pragma unroll
      for (int dt = 0; dt < 4; dt++)
#pragma unroll
        for (int q4 = 0; q4 < 4; q4++) {
          int dbase = 32 * dt + 8 * q4 + 4 * hi;
          u16x4 o;
#pragma unroll
          for (int j = 0; j < 4; j++) {
            int r = q4 * 4 + j, d = dbase + j;
            float vo = SM_acc[q_local * 128 + (d ^ l31)];
            o[j] = f2bf((accO[dt][r] + vo) * inv);
          }
          *(u16x4*)(ao + (size_t)q_row * HDIM + h * HD + dbase) = o;
        }
    }
  }
}

// ---------------- launch ----------------
extern "C" void kernel_launch(void* const* d_in, const int* in_sizes, int n_in,
                              void* d_out, int out_size, void* d_ws, size_t ws_size,
                              hipStream_t stream) {
  const float* x      = (const float*)d_in[0];
  const float* ve     = (const float*)d_in[1];
  const float* lam    = (const float*)d_in[2];
  const float* qkv_w  = (const float*)d_in[3];
  const float* proj_w = (const float*)d_in[4];
  float* out = (float*)d_out;

  char* p = (char*)d_ws;
  float* cosT = (float*)p;            p += (size_t)T_SEQ * 64 * 4;
  float* sinT = (float*)p;            p += (size_t)T_SEQ * 64 * 4;
  unsigned short* xb   = (unsigned short*)p; p += (size_t)T_SEQ * DIM * 2;
  unsigned short* wqb  = (unsigned short*)p; p += (size_t)3 * HDIM * DIM * 2;
  unsigned short* pwb  = (unsigned short*)p; p += (size_t)DIM * HDIM * 2;
  unsigned short* qkvb = (unsigned short*)p; p += (size_t)3 * NH * T_SEQ * HD * 2;
  unsigned short* vtb  = (unsigned short*)p; p += (size_t)NH * HD * T_SEQ * 2;
  unsigned short* aob  = (unsigned short*)p; p += (size_t)T_SEQ * HDIM * 2;

  // fused prep: x/qkv_w/proj_w converts + rope tables (boundaries 256-aligned)
  constexpr int PREP_N = T_SEQ * DIM / 4 + 3 * HDIM * DIM / 4 + DIM * HDIM / 4 + T_SEQ * 64;
  prep_all<<<PREP_N / 256, 256, 0, stream>>>(x, qkv_w, proj_w, xb, wqb, pwb, cosT, sinT);

  // QKV: BK=32 2-block/CU kernel; 768 blocks (XCD-swizzled)
  gemmQ<<<768, 512, 0, stream>>>(xb, wqb, qkvb);
  norm_rope<<<2 * NH * T_SEQ / 16, 256, 0, stream>>>(qkvb, cosT, sinT);
  vmix_transpose<<<dim3(T_SEQ / 64, HD / 64, NH), 256, 0, stream>>>(
      qkvb + (size_t)2 * NH * T_SEQ * HD, ve, lam, vtb);
  attn_fwd<<<256, 512, 0, stream>>>(qkvb, qkvb + (size_t)NH * T_SEQ * HD, vtb, aob);
  // proj: 256 blocks = 1/CU exactly
  gemm256<<<256, 512, 0, stream>>>(aob, pwb, HDIM, out, HDIM);
}

// Round 18
// 311.266 us; speedup vs baseline: 1.0375x; 1.0375x over previous
//
#include <hip/hip_runtime.h>
#include <cstdint>
#include <cstddef>

// ---------------- constants ----------------
constexpr int T_SEQ = 4096;
constexpr int NH    = 16;
constexpr int HD    = 128;
constexpr int DIM   = 2048;
constexpr int HDIM  = 2048;   // NH*HD

typedef __attribute__((ext_vector_type(8)))  short  short8;
typedef __attribute__((ext_vector_type(4)))  float  f32x4;
typedef __attribute__((ext_vector_type(16))) float  f32x16;
typedef __attribute__((ext_vector_type(8)))  unsigned short u16x8;
typedef __attribute__((ext_vector_type(4)))  unsigned short u16x4;
typedef __attribute__((ext_vector_type(4)))  unsigned uint4v;
typedef __attribute__((ext_vector_type(2)))  int int2v;

__device__ __forceinline__ unsigned short f2bf(float f) {
  unsigned u = __float_as_uint(f);
  return (unsigned short)((u + 0x7FFFu + ((u >> 16) & 1u)) >> 16);  // RNE
}
__device__ __forceinline__ float bf2f(unsigned short h) {
  return __uint_as_float(((unsigned)h) << 16);
}
__device__ __forceinline__ void gload_lds16(const void* g, void* l) {
  __builtin_amdgcn_global_load_lds((const __attribute__((address_space(1))) void*)g,
                                   (__attribute__((address_space(3))) void*)l, 16, 0, 0);
}
__device__ __forceinline__ int2v plswap(int a, int b) {
  return __builtin_amdgcn_permlane32_swap(a, b, false, false);
}
__device__ __forceinline__ void bar() {           // raw barrier: no implicit vmcnt(0)
  asm volatile("" ::: "memory");
  __builtin_amdgcn_s_barrier();
  asm volatile("" ::: "memory");
}
#define VMCNT(n) asm volatile("s_waitcnt vmcnt(" #n ")" ::: "memory")

// ---------------- fused prep: 3x fp32->bf16 convert + RoPE tables, one launch ----------
__global__ __launch_bounds__(256) void prep_all(const float* __restrict__ x,
                                                const float* __restrict__ qkv_w,
                                                const float* __restrict__ proj_w,
                                                unsigned short* __restrict__ xb,
                                                unsigned short* __restrict__ wqb,
                                                unsigned short* __restrict__ pwb,
                                                float* __restrict__ cosT,
                                                float* __restrict__ sinT) {
  constexpr int N1 = T_SEQ * DIM / 4;              // 2,097,152
  constexpr int N2 = N1 + 3 * HDIM * DIM / 4;      // +3,145,728
  constexpr int N3 = N2 + DIM * HDIM / 4;          // +1,048,576
  int gid = blockIdx.x * 256 + threadIdx.x;
  const float* src; unsigned short* dst; int i4;
  if (gid < N1)      { src = x;      dst = xb;  i4 = gid; }
  else if (gid < N2) { src = qkv_w;  dst = wqb; i4 = gid - N1; }
  else if (gid < N3) { src = proj_w; dst = pwb; i4 = gid - N2; }
  else {
    int idx = gid - N3;                            // T_SEQ*64 entries
    int t = idx >> 6, i = idx & 63;
    float ang = (i < 32) ? exp2f(-10.0f * (float)i / 31.0f) : 0.0f;  // (1/1024)^(i/31)
    float th = (float)t * ang;
    cosT[idx] = cosf(th);
    sinT[idx] = sinf(th);
    return;
  }
  float4 v = ((const float4*)src)[i4];
  u16x4 o; o.x = f2bf(v.x); o.y = f2bf(v.y); o.z = f2bf(v.z); o.w = f2bf(v.w);
  ((u16x4*)dst)[i4] = o;
}

// ---------------- GEMM: C = A * B^T (deep-pipelined, T2+T3+T4+T5) ----------------
// Barrier-minimal K-loop (R16, best measured): only 2 load-bearing barriers/K-tile.
// (a) vmcnt(6)+bar before phase-1 MFMA: every wave's tile-(t+1) staging landed.
// (b) end-of-tile bar: all waves' reads of buf c consumed by their own MFMA.
// BK=32 higher-occupancy variant (R17) REGRESSED: 2x sync events per K-FLOP +
// halved MFMA burst per stage outweighed the extra waves. Keep this structure.
template <int MODE>
__global__ __launch_bounds__(512) void gemm256(const unsigned short* __restrict__ A,
                                               const unsigned short* __restrict__ B,
                                               int K, unsigned short* __restrict__ outb,
                                               float* __restrict__ outf, int N) {
  __shared__ __align__(16) char SM[3 * 49152];   // 144KB: 3 x [A 16KB | B 32KB]
  const int tid = threadIdx.x, w = tid >> 6, lane = tid & 63;
  const int wm = w >> 2, wn = w & 3;
  const int lr = lane >> 4, lc = lane & 15, lc7 = lc & 7;
  const int cpx = gridDim.x >> 3;
  const int idx = (blockIdx.x & 7) * cpx + (blockIdx.x >> 3);
  const int m0 = (idx & 31) * 128, n0 = (idx >> 5) * 256;

  const int arow = lane >> 3;
  const int xcol = ((lane & 7) ^ ((lane >> 3) & 7)) * 8;  // pre-swizzled source col

  auto stageA = [&](int buf, int t) {
    char* base = SM + buf * 49152;
#pragma unroll
    for (int i = 0; i < 2; i++) {
      int c = w + i * 8;
      gload_lds16(A + (size_t)(m0 + c * 8 + arow) * K + t * 64 + xcol, base + c * 1024);
    }
  };
  auto stageB0 = [&](int buf, int t) {
    char* base = SM + buf * 49152 + 16384;
    gload_lds16(B + (size_t)(n0 + w * 8 + arow) * K + t * 64 + xcol, base + w * 1024);
  };
  auto stageB1 = [&](int buf, int t) {
    char* base = SM + buf * 49152 + 16384;
#pragma unroll
    for (int i = 1; i < 4; i++) {
      int c = w + i * 8;
      gload_lds16(B + (size_t)(n0 + c * 8 + arow) * K + t * 64 + xcol, base + c * 1024);
    }
  };

  f32x4 acc[4][4] = {};
  const int NT = K >> 6;

  stageA(0, 0); stageB0(0, 0); stageB1(0, 0);
  stageA(1, 1); stageB0(1, 1); stageB1(1, 1);
  VMCNT(6);
  bar();

#pragma unroll 1
  for (int t = 0; t < NT; t++) {
    const int c = t % 3, s = (t + 2) % 3;
    const bool st = (t + 2) < NT;
    const char* Ab = SM + c * 49152;
    const char* Bb = Ab + 16384;

    // ---- phase 0 (kk = 0): reads + stage + MFMA, no barriers ----
    short8 a[4], b[4];
#pragma unroll
    for (int mi = 0; mi < 4; mi++)
      a[mi] = *(const short8*)(Ab + (wm * 64 + mi * 16 + lc) * 128 + ((0 + lr) ^ lc7) * 16);
#pragma unroll
    for (int ni = 0; ni < 4; ni++)
      b[ni] = *(const short8*)(Bb + (wn * 64 + ni * 16 + lc) * 128 + ((0 + lr) ^ lc7) * 16);
    if (st) { stageA(s, t + 2); stageB0(s, t + 2); }
    __builtin_amdgcn_s_setprio(1);
#pragma unroll
    for (int mi = 0; mi < 4; mi++)
#pragma unroll
      for (int ni = 0; ni < 4; ni++)
        acc[mi][ni] = __builtin_amdgcn_mfma_f32_16x16x32_bf16(a[mi], b[ni], acc[mi][ni], 0, 0, 0);
    __builtin_amdgcn_s_setprio(0);

    // ---- phase 1 (kk = 1) ----
#pragma unroll
    for (int mi = 0; mi < 4; mi++)
      a[mi] = *(const short8*)(Ab + (wm * 64 + mi * 16 + lc) * 128 + ((4 + lr) ^ lc7) * 16);
#pragma unroll
    for (int ni = 0; ni < 4; ni++)
      b[ni] = *(const short8*)(Bb + (wn * 64 + ni * 16 + lc) * 128 + ((4 + lr) ^ lc7) * 16);
    if (st) stageB1(s, t + 2);
    if (st) { VMCNT(6); } else { VMCNT(0); }   // confirm tile t+1 (tail: drain)
    bar();                                     // (a) all waves' t+1 staging landed
    __builtin_amdgcn_s_setprio(1);
#pragma unroll
    for (int mi = 0; mi < 4; mi++)
#pragma unroll
      for (int ni = 0; ni < 4; ni++)
        acc[mi][ni] = __builtin_amdgcn_mfma_f32_16x16x32_bf16(a[mi], b[ni], acc[mi][ni], 0, 0, 0);
    __builtin_amdgcn_s_setprio(0);
    bar();                                     // (b) protect buf c vs t+1's stage
  }

#pragma unroll
  for (int mi = 0; mi < 4; mi++)
#pragma unroll
    for (int ni = 0; ni < 4; ni++)
#pragma unroll
      for (int r = 0; r < 4; r++) {
        int t = m0 + wm * 64 + mi * 16 + lr * 4 + r;
        int n = n0 + wn * 64 + ni * 16 + lc;
        float v = acc[mi][ni][r];
        if (MODE == 0) {
          int cc = n >> 11, e = n & 2047, h = e >> 7, d = e & 127;
          outb[(((size_t)cc * NH + h) * T_SEQ + t) * HD + d] = f2bf(v);
        } else {
          outf[(size_t)t * N + n] = v;
        }
      }
}

// ---------------- RMSNorm + RoPE (in-place on q,k; layout [c][h][t][d]) ----------------
__global__ __launch_bounds__(256) void norm_rope(unsigned short* __restrict__ qkvb,
                                                 const float* __restrict__ cosT,
                                                 const float* __restrict__ sinT) {
  const int tid = threadIdx.x;
  const int li = tid & 15;                          // position within row (8 elems each)
  const int row = blockIdx.x * 16 + (tid >> 4);     // row over [c][h][t]
  const int t = row & (T_SEQ - 1);
  unsigned short* rp = qkvb + (size_t)row * HD + li * 8;
  u16x8 raw = *(const u16x8*)rp;

  float v[8]; float ss = 0.0f;
#pragma unroll
  for (int j = 0; j < 8; j++) { v[j] = bf2f(raw[j]); ss += v[j] * v[j]; }
#pragma unroll
  for (int off = 1; off < 16; off <<= 1) ss += __shfl_xor(ss, off, 16);
  float rs = rsqrtf(ss * (1.0f / 128.0f) + 1e-6f);
  if (row < NH * T_SEQ) rs *= 0.088388347648318447f * 1.44269504f;  // q rows only

  uint4v rw = __builtin_bit_cast(uint4v, raw);
  uint4v pwv;
  pwv.x = (unsigned)__shfl_xor((int)rw.x, 8, 16);
  pwv.y = (unsigned)__shfl_xor((int)rw.y, 8, 16);
  pwv.z = (unsigned)__shfl_xor((int)rw.z, 8, 16);
  pwv.w = (unsigned)__shfl_xor((int)rw.w, 8, 16);
  u16x8 praw = __builtin_bit_cast(u16x8, pwv);
  float pv[8];
#pragma unroll
  for (int j = 0; j < 8; j++) pv[j] = bf2f(praw[j]);

  const int e0 = (li & 7) * 8;
  const bool hi8 = li >= 8;
  float4 c0 = *(const float4*)(cosT + t * 64 + e0);
  float4 c1 = *(const float4*)(cosT + t * 64 + e0 + 4);
  float4 s0 = *(const float4*)(sinT + t * 64 + e0);
  float4 s1 = *(const float4*)(sinT + t * 64 + e0 + 4);
  float cc[8] = {c0.x, c0.y, c0.z, c0.w, c1.x, c1.y, c1.z, c1.w};
  float sn[8] = {s0.x, s0.y, s0.z, s0.w, s1.x, s1.y, s1.z, s1.w};

  u16x8 o;
#pragma unroll
  for (int j = 0; j < 8; j++) {
    float x1 = hi8 ? pv[j] : v[j];
    float x2 = hi8 ? v[j] : pv[j];
    float r = hi8 ? (-x1 * sn[j] + x2 * cc[j]) : (x1 * cc[j] + x2 * sn[j]);
    o[j] = f2bf(r * rs);
  }
  *(u16x8*)rp = o;
}

// ---------------- v' = l0*v + l1*ve, transposed to v_t[h][d][t] ----------------
__global__ __launch_bounds__(256) void vmix_transpose(const unsigned short* __restrict__ vb,
                                                      const float* __restrict__ ve,
                                                      const float* __restrict__ lam,
                                                      unsigned short* __restrict__ vt) {
  __shared__ float tile[64][65];
  const int h = blockIdx.z, t0 = blockIdx.x * 64, d0 = blockIdx.y * 64;
  const float l0 = lam[0], l1 = lam[1];
  const int tid = threadIdx.x;
  const int tl = tid >> 4, dl4 = (tid & 15) * 4;
#pragma unroll
  for (int i = 0; i < 4; i++) {
    int t_local = tl + i * 16;
    int t = t0 + t_local;
    const unsigned short* vp = vb + ((size_t)h * T_SEQ + t) * HD + d0 + dl4;
    const float* vep = ve + (size_t)t * HDIM + h * HD + d0 + dl4;
    u16x4 vv = *(const u16x4*)vp;
    float4 vef = *(const float4*)vep;
    tile[t_local][dl4 + 0] = l0 * bf2f(vv.x) + l1 * vef.x;
    tile[t_local][dl4 + 1] = l0 * bf2f(vv.y) + l1 * vef.y;
    tile[t_local][dl4 + 2] = l0 * bf2f(vv.z) + l1 * vef.z;
    tile[t_local][dl4 + 3] = l0 * bf2f(vv.w) + l1 * vef.w;
  }
  __syncthreads();
#pragma unroll
  for (int i = 0; i < 2; i++) {
    int idx = tid + i * 256;
    int d_local = idx >> 3, tloc = (idx & 7) * 8;
    u16x8 o;
#pragma unroll
    for (int j = 0; j < 8; j++) o[j] = f2bf(tile[tloc + j][d_local]);
    *(u16x8*)(vt + ((size_t)h * HD + d0 + d_local) * T_SEQ + t0 + tloc) = o;
  }
}

// ---------------- flash attention (causal), swapped-operand 32x32x16 ----------------
// Stable best (143us): fixed-max softmax (FM=16.5), K-row permutation (lane-local PV),
// kv-parity group split with drift barriers.
__global__ __launch_bounds__(512)
__attribute__((amdgpu_waves_per_eu(2, 2)))
void attn_fwd(const unsigned short* __restrict__ qb,
              const unsigned short* __restrict__ kb,
              const unsigned short* __restrict__ vt,
              unsigned short* __restrict__ ao) {
  __shared__ __align__(16) char SMEM[131072];   // [group][ K 2x16KB | V 2x16KB ]
  __shared__ int gctr[2];                       // group-barrier monotonic counters
  const int bid = blockIdx.x;
  const int h  = (bid & 7) + ((bid >> 7) << 3);  // XCD swizzle: head h on XCD h%8
  const int pr = (bid >> 3) & 15;
  const int tid = threadIdx.x, w = tid >> 6, lane = tid & 63;
  const int g = w >> 2, wq = w & 3;
  const int l31 = lane & 31, hi = lane >> 5, r7 = l31 & 7;
  const unsigned short* qh = qb + (size_t)h * T_SEQ * HD;
  const unsigned short* kh = kb + (size_t)h * T_SEQ * HD;
  const unsigned short* vh = vt + (size_t)h * HD * T_SEQ;

  if (tid < 2) gctr[tid] = 0;
  __syncthreads();
  int bcnt = 0;
  auto GBAR = [&]() {   // group-local barrier: 4 waves of group g
    asm volatile("s_waitcnt lgkmcnt(0)" ::: "memory");
    ++bcnt;
    if (lane == 0)
      __hip_atomic_fetch_add(&gctr[g], 1, __ATOMIC_RELEASE, __HIP_MEMORY_SCOPE_WORKGROUP);
    while (__hip_atomic_load(&gctr[g], __ATOMIC_ACQUIRE, __HIP_MEMORY_SCOPE_WORKGROUP) < 4 * bcnt)
      __builtin_amdgcn_s_sleep(1);
  };

  char* Kbase = SMEM + g * 65536;
  char* Vbase = SMEM + g * 65536 + 32768;

  const int kcrow = lane >> 4, kcol16 = lane & 15;   // K staging: 4 rows / 1KB chunk
  const int vcrow = lane >> 3, vslot0 = lane & 7;    // V staging: 8 rows / 1KB chunk

  auto STAGE = [&](int buf, int t) {                 // t = global kv tile index
#pragma unroll
    for (int i = 0; i < 4; i++) {
      int krow = (wq * 4 + i) * 4 + kcrow;           // LDS position
      int ksrc = (krow & ~12) | ((krow & 4) << 1) | ((krow & 8) >> 1);  // sigma: b2<->b3
      int kcol = (kcol16 ^ (krow & 7)) * 8;          // pre-swizzled source (rule #21)
      gload_lds16(kh + (size_t)(t * 64 + ksrc) * HD + kcol,
                  Kbase + buf * 16384 + (wq * 4 + i) * 1024);
      int vrow = (wq * 4 + i) * 8 + vcrow;
      int vcol = (vslot0 ^ (vrow & 7)) * 8;
      gload_lds16(vh + (size_t)vrow * T_SEQ + t * 64 + vcol,
                  Vbase + buf * 16384 + (wq * 4 + i) * 1024);
    }
  };

  const float FM = 16.5f;   // fixed softmax max (exp2 domain), > score bound 16.46

#pragma unroll 1
  for (int which = 0; which < 2; ++which) {
    const int qt = which ? pr : (31 - pr);     // heavy tile first
    const int ng = qt + 1;                     // tiles for THIS group (parity g)
    const int q_row = qt * 128 + wq * 32 + l31;

    short8 qf[8];                              // B-frag: Q[q_row][16dk + 8hi + 0..7]
#pragma unroll
    for (int dk = 0; dk < 8; dk++)
      qf[dk] = *(const short8*)(qh + (size_t)q_row * HD + dk * 16 + hi * 8);

    f32x16 accO[4] = {};                       // O^T: col=q, rows d (4 tiles of 32)
    float l_r = 0.0f;

    __syncthreads();                           // prev combine reads done (cross-group)
    STAGE(0, g);

#pragma unroll 1
    for (int it = 0; it < ng; it++) {
      const int t = 2 * it + g;                // this group's kv tile
      const int cur = it & 1;
      asm volatile("s_waitcnt vmcnt(0)" ::: "memory");  // own stage(cur) landed
      GBAR();                                           // group's stage(cur) landed
      if (it + 1 < ng) STAGE(cur ^ 1, t + 2);           // prefetch under compute

      // ---- S^T = K Q^T : 2 kv-subtiles x 8 d-steps (scores pre-scaled via Q) ----
      f32x16 accS0 = {}, accS1 = {};
      const char* Kb = Kbase + cur * 16384 + l31 * 256;
      __builtin_amdgcn_s_setprio(1);
#pragma unroll
      for (int dk = 0; dk < 8; dk++) {
        int sl = ((2 * dk + hi) ^ r7) * 16;
        short8 k0 = *(const short8*)(Kb + sl);
        short8 k1 = *(const short8*)(Kb + 32 * 256 + sl);
        accS0 = __builtin_amdgcn_mfma_f32_32x32x16_bf16(k0, qf[dk], accS0, 0, 0, 0);
        accS1 = __builtin_amdgcn_mfma_f32_32x32x16_bf16(k1, qf[dk], accS1, 0, 0, 0);
      }
      __builtin_amdgcn_s_setprio(0);

      // ---- causal mask + exp2(s - FM); permuted layout: kv = 64t+(r&7)+8hi+16(r>>3) ----
      float p[32];
      const bool need_mask = (t * 64 + 63) > (qt * 128 + wq * 32);
      if (need_mask) {
#pragma unroll
        for (int r = 0; r < 16; r++) {
          int kv0 = t * 64 + (r & 7) + 8 * hi + 16 * (r >> 3);
          p[r]      = (kv0      > q_row) ? 0.0f : exp2f(accS0[r] - FM);
          p[16 + r] = (kv0 + 32 > q_row) ? 0.0f : exp2f(accS1[r] - FM);
        }
      } else {
#pragma unroll
        for (int r = 0; r < 16; r++) {
          p[r]      = exp2f(accS0[r] - FM);
          p[16 + r] = exp2f(accS1[r] - FM);
        }
      }

      // ---- row sum (partner holds complementary kv set; one cross-half swap) ----
      float s16[16];
#pragma unroll
      for (int i = 0; i < 16; i++) s16[i] = p[i] + p[i + 16];
#pragma unroll
      for (int st = 8; st >= 1; st >>= 1)
#pragma unroll
        for (int i = 0; i < st; i++) s16[i] += s16[i + st];
      int2v sr_ = plswap(__float_as_int(s16[0]), __float_as_int(s16[0]));
      l_r += s16[0] + __int_as_float(hi ? sr_.x : sr_.y);

      // ---- PV: O^T += V^T P^T ; pb[ks] = p[8ks..8ks+7] (lane-local, no exchange) ----
      const char* Vb = Vbase + cur * 16384 + l31 * 128;
#pragma unroll
      for (int ks = 0; ks < 4; ks++) {
        uint4v pw;
#pragma unroll
        for (int w2 = 0; w2 < 4; w2++) {
          unsigned pk_;
          asm("v_cvt_pk_bf16_f32 %0, %1, %2"
              : "=v"(pk_) : "v"(p[8 * ks + 2 * w2]), "v"(p[8 * ks + 2 * w2 + 1]));
          pw[w2] = pk_;
        }
        short8 pb = __builtin_bit_cast(short8, pw);
        int sl = ((2 * ks + hi) ^ r7) * 16;
        __builtin_amdgcn_s_setprio(1);
#pragma unroll
        for (int dt = 0; dt < 4; dt++) {
          short8 vf = *(const short8*)(Vb + dt * 32 * 128 + sl);
          accO[dt] = __builtin_amdgcn_mfma_f32_32x32x16_bf16(vf, pb, accO[dt], 0, 0, 0);
        }
        __builtin_amdgcn_s_setprio(0);
      }
    }

    // ---- combine even/odd partials (fixed max -> merge is a plain sum) ----
    __syncthreads();                                  // all compute done (cross-group)
    float* SM_acc = (float*)(SMEM + 65536);           // odd group's staging (dead now)
    float* SM_l   = (float*)SMEM;                     // even group's staging (dead now)
    const int q_local = wq * 32 + l31;
    if (g == 1) {
#pragma unroll
      for (int dt = 0; dt < 4; dt++)
#pragma unroll
        for (int r = 0; r < 16; r++) {
          int d = 32 * dt + (r & 3) + 8 * (r >> 2) + 4 * hi;
          SM_acc[q_local * 128 + (d ^ l31)] = accO[dt][r];   // word-swz: conflict-free
        }
      if (hi == 0) SM_l[q_local] = l_r;
    }
    __syncthreads();                                  // partials visible
    if (g == 0) {
      float lo = SM_l[q_local];
      float inv = 1.0f / (l_r + lo);                  // l_r > 0 (diagonal in even group)
#pragma unroll
      for (int dt = 0; dt < 4; dt++)
#pragma unroll
        for (int q4 = 0; q4 < 4; q4++) {
          int dbase = 32 * dt + 8 * q4 + 4 * hi;
          u16x4 o;
#pragma unroll
          for (int j = 0; j < 4; j++) {
            int r = q4 * 4 + j, d = dbase + j;
            float vo = SM_acc[q_local * 128 + (d ^ l31)];
            o[j] = f2bf((accO[dt][r] + vo) * inv);
          }
          *(u16x4*)(ao + (size_t)q_row * HDIM + h * HD + dbase) = o;
        }
    }
  }
}

// ---------------- launch ----------------
extern "C" void kernel_launch(void* const* d_in, const int* in_sizes, int n_in,
                              void* d_out, int out_size, void* d_ws, size_t ws_size,
                              hipStream_t stream) {
  const float* x      = (const float*)d_in[0];
  const float* ve     = (const float*)d_in[1];
  const float* lam    = (const float*)d_in[2];
  const float* qkv_w  = (const float*)d_in[3];
  const float* proj_w = (const float*)d_in[4];
  float* out = (float*)d_out;

  char* p = (char*)d_ws;
  float* cosT = (float*)p;            p += (size_t)T_SEQ * 64 * 4;
  float* sinT = (float*)p;            p += (size_t)T_SEQ * 64 * 4;
  unsigned short* xb   = (unsigned short*)p; p += (size_t)T_SEQ * DIM * 2;
  unsigned short* wqb  = (unsigned short*)p; p += (size_t)3 * HDIM * DIM * 2;
  unsigned short* pwb  = (unsigned short*)p; p += (size_t)DIM * HDIM * 2;
  unsigned short* qkvb = (unsigned short*)p; p += (size_t)3 * NH * T_SEQ * HD * 2;
  unsigned short* vtb  = (unsigned short*)p; p += (size_t)NH * HD * T_SEQ * 2;
  unsigned short* aob  = (unsigned short*)p; p += (size_t)T_SEQ * HDIM * 2;

  // fused prep: x/qkv_w/proj_w converts + rope tables (boundaries 256-aligned)
  constexpr int PREP_N = T_SEQ * DIM / 4 + 3 * HDIM * DIM / 4 + DIM * HDIM / 4 + T_SEQ * 64;
  prep_all<<<PREP_N / 256, 256, 0, stream>>>(x, qkv_w, proj_w, xb, wqb, pwb, cosT, sinT);

  // QKV: 768 blocks = 3/CU exactly (R16 barrier-minimal BK=64 kernel)
  gemm256<0><<<768, 512, 0, stream>>>(xb, wqb, DIM, qkvb, nullptr, 3 * HDIM);
  norm_rope<<<2 * NH * T_SEQ / 16, 256, 0, stream>>>(qkvb, cosT, sinT);
  vmix_transpose<<<dim3(T_SEQ / 64, HD / 64, NH), 256, 0, stream>>>(
      qkvb + (size_t)2 * NH * T_SEQ * HD, ve, lam, vtb);
  attn_fwd<<<256, 512, 0, stream>>>(qkvb, qkvb + (size_t)NH * T_SEQ * HD, vtb, aob);
  // proj: 256 blocks = 1/CU exactly
  gemm256<1><<<256, 512, 0, stream>>>(aob, pwb, HDIM, nullptr, out, HDIM);
}

// Round 19
// 309.967 us; speedup vs baseline: 1.0419x; 1.0042x over previous
//
#include <hip/hip_runtime.h>
#include <cstdint>
#include <cstddef>

// ---------------- constants ----------------
constexpr int T_SEQ = 4096;
constexpr int NH    = 16;
constexpr int HD    = 128;
constexpr int DIM   = 2048;
constexpr int HDIM  = 2048;   // NH*HD

typedef __attribute__((ext_vector_type(8)))  short  short8;
typedef __attribute__((ext_vector_type(4)))  float  f32x4;
typedef __attribute__((ext_vector_type(16))) float  f32x16;
typedef __attribute__((ext_vector_type(8)))  unsigned short u16x8;
typedef __attribute__((ext_vector_type(4)))  unsigned short u16x4;
typedef __attribute__((ext_vector_type(4)))  unsigned uint4v;
typedef __attribute__((ext_vector_type(2)))  int int2v;

__device__ __forceinline__ unsigned short f2bf(float f) {
  unsigned u = __float_as_uint(f);
  return (unsigned short)((u + 0x7FFFu + ((u >> 16) & 1u)) >> 16);  // RNE
}
__device__ __forceinline__ float bf2f(unsigned short h) {
  return __uint_as_float(((unsigned)h) << 16);
}
__device__ __forceinline__ void gload_lds16(const void* g, void* l) {
  __builtin_amdgcn_global_load_lds((const __attribute__((address_space(1))) void*)g,
                                   (__attribute__((address_space(3))) void*)l, 16, 0, 0);
}
__device__ __forceinline__ int2v plswap(int a, int b) {
  return __builtin_amdgcn_permlane32_swap(a, b, false, false);
}
__device__ __forceinline__ void bar() {           // raw barrier: no implicit vmcnt(0)
  asm volatile("" ::: "memory");
  __builtin_amdgcn_s_barrier();
  asm volatile("" ::: "memory");
}
#define VMCNT(n) asm volatile("s_waitcnt vmcnt(" #n ")" ::: "memory")

// ---------------- fused prep: 3x fp32->bf16 convert + RoPE tables, one launch ----------
__global__ __launch_bounds__(256) void prep_all(const float* __restrict__ x,
                                                const float* __restrict__ qkv_w,
                                                const float* __restrict__ proj_w,
                                                unsigned short* __restrict__ xb,
                                                unsigned short* __restrict__ wqb,
                                                unsigned short* __restrict__ pwb,
                                                float* __restrict__ cosT,
                                                float* __restrict__ sinT) {
  constexpr int N1 = T_SEQ * DIM / 4;              // 2,097,152
  constexpr int N2 = N1 + 3 * HDIM * DIM / 4;      // +3,145,728
  constexpr int N3 = N2 + DIM * HDIM / 4;          // +1,048,576
  int gid = blockIdx.x * 256 + threadIdx.x;
  const float* src; unsigned short* dst; int i4;
  if (gid < N1)      { src = x;      dst = xb;  i4 = gid; }
  else if (gid < N2) { src = qkv_w;  dst = wqb; i4 = gid - N1; }
  else if (gid < N3) { src = proj_w; dst = pwb; i4 = gid - N2; }
  else {
    int idx = gid - N3;                            // T_SEQ*64 entries
    int t = idx >> 6, i = idx & 63;
    float ang = (i < 32) ? exp2f(-10.0f * (float)i / 31.0f) : 0.0f;  // (1/1024)^(i/31)
    float th = (float)t * ang;
    cosT[idx] = cosf(th);
    sinT[idx] = sinf(th);
    return;
  }
  float4 v = ((const float4*)src)[i4];
  u16x4 o; o.x = f2bf(v.x); o.y = f2bf(v.y); o.z = f2bf(v.z); o.w = f2bf(v.w);
  ((u16x4*)dst)[i4] = o;
}

// ---------------- GEMM: C = A * B^T (deep-pipelined, T2+T3+T4+T5) ----------------
// Barrier-minimal K-loop (R16, best measured): only 2 load-bearing barriers/K-tile.
template <int MODE>
__global__ __launch_bounds__(512) void gemm256(const unsigned short* __restrict__ A,
                                               const unsigned short* __restrict__ B,
                                               int K, unsigned short* __restrict__ outb,
                                               float* __restrict__ outf, int N) {
  __shared__ __align__(16) char SM[3 * 49152];   // 144KB: 3 x [A 16KB | B 32KB]
  const int tid = threadIdx.x, w = tid >> 6, lane = tid & 63;
  const int wm = w >> 2, wn = w & 3;
  const int lr = lane >> 4, lc = lane & 15, lc7 = lc & 7;
  const int cpx = gridDim.x >> 3;
  const int idx = (blockIdx.x & 7) * cpx + (blockIdx.x >> 3);
  const int m0 = (idx & 31) * 128, n0 = (idx >> 5) * 256;

  const int arow = lane >> 3;
  const int xcol = ((lane & 7) ^ ((lane >> 3) & 7)) * 8;  // pre-swizzled source col

  auto stageA = [&](int buf, int t) {
    char* base = SM + buf * 49152;
#pragma unroll
    for (int i = 0; i < 2; i++) {
      int c = w + i * 8;
      gload_lds16(A + (size_t)(m0 + c * 8 + arow) * K + t * 64 + xcol, base + c * 1024);
    }
  };
  auto stageB0 = [&](int buf, int t) {
    char* base = SM + buf * 49152 + 16384;
    gload_lds16(B + (size_t)(n0 + w * 8 + arow) * K + t * 64 + xcol, base + w * 1024);
  };
  auto stageB1 = [&](int buf, int t) {
    char* base = SM + buf * 49152 + 16384;
#pragma unroll
    for (int i = 1; i < 4; i++) {
      int c = w + i * 8;
      gload_lds16(B + (size_t)(n0 + c * 8 + arow) * K + t * 64 + xcol, base + c * 1024);
    }
  };

  f32x4 acc[4][4] = {};
  const int NT = K >> 6;

  stageA(0, 0); stageB0(0, 0); stageB1(0, 0);
  stageA(1, 1); stageB0(1, 1); stageB1(1, 1);
  VMCNT(6);
  bar();

#pragma unroll 1
  for (int t = 0; t < NT; t++) {
    const int c = t % 3, s = (t + 2) % 3;
    const bool st = (t + 2) < NT;
    const char* Ab = SM + c * 49152;
    const char* Bb = Ab + 16384;

    // ---- phase 0 (kk = 0): reads + stage + MFMA, no barriers ----
    short8 a[4], b[4];
#pragma unroll
    for (int mi = 0; mi < 4; mi++)
      a[mi] = *(const short8*)(Ab + (wm * 64 + mi * 16 + lc) * 128 + ((0 + lr) ^ lc7) * 16);
#pragma unroll
    for (int ni = 0; ni < 4; ni++)
      b[ni] = *(const short8*)(Bb + (wn * 64 + ni * 16 + lc) * 128 + ((0 + lr) ^ lc7) * 16);
    if (st) { stageA(s, t + 2); stageB0(s, t + 2); }
    __builtin_amdgcn_s_setprio(1);
#pragma unroll
    for (int mi = 0; mi < 4; mi++)
#pragma unroll
      for (int ni = 0; ni < 4; ni++)
        acc[mi][ni] = __builtin_amdgcn_mfma_f32_16x16x32_bf16(a[mi], b[ni], acc[mi][ni], 0, 0, 0);
    __builtin_amdgcn_s_setprio(0);

    // ---- phase 1 (kk = 1) ----
#pragma unroll
    for (int mi = 0; mi < 4; mi++)
      a[mi] = *(const short8*)(Ab + (wm * 64 + mi * 16 + lc) * 128 + ((4 + lr) ^ lc7) * 16);
#pragma unroll
    for (int ni = 0; ni < 4; ni++)
      b[ni] = *(const short8*)(Bb + (wn * 64 + ni * 16 + lc) * 128 + ((4 + lr) ^ lc7) * 16);
    if (st) stageB1(s, t + 2);
    if (st) { VMCNT(6); } else { VMCNT(0); }   // confirm tile t+1 (tail: drain)
    bar();                                     // (a) all waves' t+1 staging landed
    __builtin_amdgcn_s_setprio(1);
#pragma unroll
    for (int mi = 0; mi < 4; mi++)
#pragma unroll
      for (int ni = 0; ni < 4; ni++)
        acc[mi][ni] = __builtin_amdgcn_mfma_f32_16x16x32_bf16(a[mi], b[ni], acc[mi][ni], 0, 0, 0);
    __builtin_amdgcn_s_setprio(0);
    bar();                                     // (b) protect buf c vs t+1's stage
  }

#pragma unroll
  for (int mi = 0; mi < 4; mi++)
#pragma unroll
    for (int ni = 0; ni < 4; ni++)
#pragma unroll
      for (int r = 0; r < 4; r++) {
        int t = m0 + wm * 64 + mi * 16 + lr * 4 + r;
        int n = n0 + wn * 64 + ni * 16 + lc;
        float v = acc[mi][ni][r];
        if (MODE == 0) {
          int cc = n >> 11, e = n & 2047, h = e >> 7, d = e & 127;
          outb[(((size_t)cc * NH + h) * T_SEQ + t) * HD + d] = f2bf(v);
        } else {
          outf[(size_t)t * N + n] = v;
        }
      }
}

// ------- fused RMSNorm+RoPE (q,k) + vmix-transpose (v): one launch, 10240 blocks -------
// Blocks 0..8191: norm+rope on q,k rows (vectorized, Q pre-scaled by 1/sqrt(128)*log2e).
// Blocks 8192..10239: v' = l0*v + l1*ve transposed to vt[h][d][t]. Disjoint data
// (norm touches qkv c=0,1; vmix reads c=2 + ve); branch is block-uniform.
__global__ __launch_bounds__(256) void norm_vmix(unsigned short* __restrict__ qkvb,
                                                 const float* __restrict__ cosT,
                                                 const float* __restrict__ sinT,
                                                 const float* __restrict__ ve,
                                                 const float* __restrict__ lam,
                                                 unsigned short* __restrict__ vt) {
  __shared__ float tile[64][65];
  const int bid = blockIdx.x, tid = threadIdx.x;

  if (bid < 8192) {
    // ---- RMSNorm + RoPE ----
    const int li = tid & 15;                        // position within row (8 elems each)
    const int row = bid * 16 + (tid >> 4);          // row over [c][h][t], c in {0,1}
    const int t = row & (T_SEQ - 1);
    unsigned short* rp = qkvb + (size_t)row * HD + li * 8;
    u16x8 raw = *(const u16x8*)rp;

    float v[8]; float ss = 0.0f;
#pragma unroll
    for (int j = 0; j < 8; j++) { v[j] = bf2f(raw[j]); ss += v[j] * v[j]; }
#pragma unroll
    for (int off = 1; off < 16; off <<= 1) ss += __shfl_xor(ss, off, 16);
    float rs = rsqrtf(ss * (1.0f / 128.0f) + 1e-6f);
    if (row < NH * T_SEQ) rs *= 0.088388347648318447f * 1.44269504f;  // q rows only

    uint4v rw = __builtin_bit_cast(uint4v, raw);
    uint4v pwv;
    pwv.x = (unsigned)__shfl_xor((int)rw.x, 8, 16);
    pwv.y = (unsigned)__shfl_xor((int)rw.y, 8, 16);
    pwv.z = (unsigned)__shfl_xor((int)rw.z, 8, 16);
    pwv.w = (unsigned)__shfl_xor((int)rw.w, 8, 16);
    u16x8 praw = __builtin_bit_cast(u16x8, pwv);
    float pv[8];
#pragma unroll
    for (int j = 0; j < 8; j++) pv[j] = bf2f(praw[j]);

    const int e0 = (li & 7) * 8;
    const bool hi8 = li >= 8;
    float4 c0 = *(const float4*)(cosT + t * 64 + e0);
    float4 c1 = *(const float4*)(cosT + t * 64 + e0 + 4);
    float4 s0 = *(const float4*)(sinT + t * 64 + e0);
    float4 s1 = *(const float4*)(sinT + t * 64 + e0 + 4);
    float cc[8] = {c0.x, c0.y, c0.z, c0.w, c1.x, c1.y, c1.z, c1.w};
    float sn[8] = {s0.x, s0.y, s0.z, s0.w, s1.x, s1.y, s1.z, s1.w};

    u16x8 o;
#pragma unroll
    for (int j = 0; j < 8; j++) {
      float x1 = hi8 ? pv[j] : v[j];
      float x2 = hi8 ? v[j] : pv[j];
      float r = hi8 ? (-x1 * sn[j] + x2 * cc[j]) : (x1 * cc[j] + x2 * sn[j]);
      o[j] = f2bf(r * rs);
    }
    *(u16x8*)rp = o;
  } else {
    // ---- vmix + transpose ----
    const int j2 = bid - 8192;                      // 0..2047
    const int t0 = (j2 & 63) * 64, d0 = ((j2 >> 6) & 1) * 64, h = j2 >> 7;
    const unsigned short* vb = qkvb + (size_t)2 * NH * T_SEQ * HD;
    const float l0 = lam[0], l1 = lam[1];
    const int tl = tid >> 4, dl4 = (tid & 15) * 4;
#pragma unroll
    for (int i = 0; i < 4; i++) {
      int t_local = tl + i * 16;
      int t = t0 + t_local;
      const unsigned short* vp = vb + ((size_t)h * T_SEQ + t) * HD + d0 + dl4;
      const float* vep = ve + (size_t)t * HDIM + h * HD + d0 + dl4;
      u16x4 vv = *(const u16x4*)vp;
      float4 vef = *(const float4*)vep;
      tile[t_local][dl4 + 0] = l0 * bf2f(vv.x) + l1 * vef.x;
      tile[t_local][dl4 + 1] = l0 * bf2f(vv.y) + l1 * vef.y;
      tile[t_local][dl4 + 2] = l0 * bf2f(vv.z) + l1 * vef.z;
      tile[t_local][dl4 + 3] = l0 * bf2f(vv.w) + l1 * vef.w;
    }
    __syncthreads();
#pragma unroll
    for (int i = 0; i < 2; i++) {
      int idx = tid + i * 256;
      int d_local = idx >> 3, tloc = (idx & 7) * 8;
      u16x8 o;
#pragma unroll
      for (int j = 0; j < 8; j++) o[j] = f2bf(tile[tloc + j][d_local]);
      *(u16x8*)(vt + ((size_t)h * HD + d0 + d_local) * T_SEQ + t0 + tloc) = o;
    }
  }
}

// ---------------- flash attention (causal), swapped-operand 32x32x16 ----------------
// Stable best (143us): fixed-max softmax (FM=16.5), K-row permutation (lane-local PV),
// kv-parity group split with drift barriers.
__global__ __launch_bounds__(512)
__attribute__((amdgpu_waves_per_eu(2, 2)))
void attn_fwd(const unsigned short* __restrict__ qb,
              const unsigned short* __restrict__ kb,
              const unsigned short* __restrict__ vt,
              unsigned short* __restrict__ ao) {
  __shared__ __align__(16) char SMEM[131072];   // [group][ K 2x16KB | V 2x16KB ]
  __shared__ int gctr[2];                       // group-barrier monotonic counters
  const int bid = blockIdx.x;
  const int h  = (bid & 7) + ((bid >> 7) << 3);  // XCD swizzle: head h on XCD h%8
  const int pr = (bid >> 3) & 15;
  const int tid = threadIdx.x, w = tid >> 6, lane = tid & 63;
  const int g = w >> 2, wq = w & 3;
  const int l31 = lane & 31, hi = lane >> 5, r7 = l31 & 7;
  const unsigned short* qh = qb + (size_t)h * T_SEQ * HD;
  const unsigned short* kh = kb + (size_t)h * T_SEQ * HD;
  const unsigned short* vh = vt + (size_t)h * HD * T_SEQ;

  if (tid < 2) gctr[tid] = 0;
  __syncthreads();
  int bcnt = 0;
  auto GBAR = [&]() {   // group-local barrier: 4 waves of group g
    asm volatile("s_waitcnt lgkmcnt(0)" ::: "memory");
    ++bcnt;
    if (lane == 0)
      __hip_atomic_fetch_add(&gctr[g], 1, __ATOMIC_RELEASE, __HIP_MEMORY_SCOPE_WORKGROUP);
    while (__hip_atomic_load(&gctr[g], __ATOMIC_ACQUIRE, __HIP_MEMORY_SCOPE_WORKGROUP) < 4 * bcnt)
      __builtin_amdgcn_s_sleep(1);
  };

  char* Kbase = SMEM + g * 65536;
  char* Vbase = SMEM + g * 65536 + 32768;

  const int kcrow = lane >> 4, kcol16 = lane & 15;   // K staging: 4 rows / 1KB chunk
  const int vcrow = lane >> 3, vslot0 = lane & 7;    // V staging: 8 rows / 1KB chunk

  auto STAGE = [&](int buf, int t) {                 // t = global kv tile index
#pragma unroll
    for (int i = 0; i < 4; i++) {
      int krow = (wq * 4 + i) * 4 + kcrow;           // LDS position
      int ksrc = (krow & ~12) | ((krow & 4) << 1) | ((krow & 8) >> 1);  // sigma: b2<->b3
      int kcol = (kcol16 ^ (krow & 7)) * 8;          // pre-swizzled source (rule #21)
      gload_lds16(kh + (size_t)(t * 64 + ksrc) * HD + kcol,
                  Kbase + buf * 16384 + (wq * 4 + i) * 1024);
      int vrow = (wq * 4 + i) * 8 + vcrow;
      int vcol = (vslot0 ^ (vrow & 7)) * 8;
      gload_lds16(vh + (size_t)vrow * T_SEQ + t * 64 + vcol,
                  Vbase + buf * 16384 + (wq * 4 + i) * 1024);
    }
  };

  const float FM = 16.5f;   // fixed softmax max (exp2 domain), > score bound 16.46

#pragma unroll 1
  for (int which = 0; which < 2; ++which) {
    const int qt = which ? pr : (31 - pr);     // heavy tile first
    const int ng = qt + 1;                     // tiles for THIS group (parity g)
    const int q_row = qt * 128 + wq * 32 + l31;

    short8 qf[8];                              // B-frag: Q[q_row][16dk + 8hi + 0..7]
#pragma unroll
    for (int dk = 0; dk < 8; dk++)
      qf[dk] = *(const short8*)(qh + (size_t)q_row * HD + dk * 16 + hi * 8);

    f32x16 accO[4] = {};                       // O^T: col=q, rows d (4 tiles of 32)
    float l_r = 0.0f;

    __syncthreads();                           // prev combine reads done (cross-group)
    STAGE(0, g);

#pragma unroll 1
    for (int it = 0; it < ng; it++) {
      const int t = 2 * it + g;                // this group's kv tile
      const int cur = it & 1;
      asm volatile("s_waitcnt vmcnt(0)" ::: "memory");  // own stage(cur) landed
      GBAR();                                           // group's stage(cur) landed
      if (it + 1 < ng) STAGE(cur ^ 1, t + 2);           // prefetch under compute

      // ---- S^T = K Q^T : 2 kv-subtiles x 8 d-steps (scores pre-scaled via Q) ----
      f32x16 accS0 = {}, accS1 = {};
      const char* Kb = Kbase + cur * 16384 + l31 * 256;
      __builtin_amdgcn_s_setprio(1);
#pragma unroll
      for (int dk = 0; dk < 8; dk++) {
        int sl = ((2 * dk + hi) ^ r7) * 16;
        short8 k0 = *(const short8*)(Kb + sl);
        short8 k1 = *(const short8*)(Kb + 32 * 256 + sl);
        accS0 = __builtin_amdgcn_mfma_f32_32x32x16_bf16(k0, qf[dk], accS0, 0, 0, 0);
        accS1 = __builtin_amdgcn_mfma_f32_32x32x16_bf16(k1, qf[dk], accS1, 0, 0, 0);
      }
      __builtin_amdgcn_s_setprio(0);

      // ---- causal mask + exp2(s - FM); permuted layout: kv = 64t+(r&7)+8hi+16(r>>3) ----
      float p[32];
      const bool need_mask = (t * 64 + 63) > (qt * 128 + wq * 32);
      if (need_mask) {
#pragma unroll
        for (int r = 0; r < 16; r++) {
          int kv0 = t * 64 + (r & 7) + 8 * hi + 16 * (r >> 3);
          p[r]      = (kv0      > q_row) ? 0.0f : exp2f(accS0[r] - FM);
          p[16 + r] = (kv0 + 32 > q_row) ? 0.0f : exp2f(accS1[r] - FM);
        }
      } else {
#pragma unroll
        for (int r = 0; r < 16; r++) {
          p[r]      = exp2f(accS0[r] - FM);
          p[16 + r] = exp2f(accS1[r] - FM);
        }
      }

      // ---- row sum (partner holds complementary kv set; one cross-half swap) ----
      float s16[16];
#pragma unroll
      for (int i = 0; i < 16; i++) s16[i] = p[i] + p[i + 16];
#pragma unroll
      for (int st = 8; st >= 1; st >>= 1)
#pragma unroll
        for (int i = 0; i < st; i++) s16[i] += s16[i + st];
      int2v sr_ = plswap(__float_as_int(s16[0]), __float_as_int(s16[0]));
      l_r += s16[0] + __int_as_float(hi ? sr_.x : sr_.y);

      // ---- PV: O^T += V^T P^T ; pb[ks] = p[8ks..8ks+7] (lane-local, no exchange) ----
      const char* Vb = Vbase + cur * 16384 + l31 * 128;
#pragma unroll
      for (int ks = 0; ks < 4; ks++) {
        uint4v pw;
#pragma unroll
        for (int w2 = 0; w2 < 4; w2++) {
          unsigned pk_;
          asm("v_cvt_pk_bf16_f32 %0, %1, %2"
              : "=v"(pk_) : "v"(p[8 * ks + 2 * w2]), "v"(p[8 * ks + 2 * w2 + 1]));
          pw[w2] = pk_;
        }
        short8 pb = __builtin_bit_cast(short8, pw);
        int sl = ((2 * ks + hi) ^ r7) * 16;
        __builtin_amdgcn_s_setprio(1);
#pragma unroll
        for (int dt = 0; dt < 4; dt++) {
          short8 vf = *(const short8*)(Vb + dt * 32 * 128 + sl);
          accO[dt] = __builtin_amdgcn_mfma_f32_32x32x16_bf16(vf, pb, accO[dt], 0, 0, 0);
        }
        __builtin_amdgcn_s_setprio(0);
      }
    }

    // ---- combine even/odd partials (fixed max -> merge is a plain sum) ----
    __syncthreads();                                  // all compute done (cross-group)
    float* SM_acc = (float*)(SMEM + 65536);           // odd group's staging (dead now)
    float* SM_l   = (float*)SMEM;                     // even group's staging (dead now)
    const int q_local = wq * 32 + l31;
    if (g == 1) {
#pragma unroll
      for (int dt = 0; dt < 4; dt++)
#pragma unroll
        for (int r = 0; r < 16; r++) {
          int d = 32 * dt + (r & 3) + 8 * (r >> 2) + 4 * hi;
          SM_acc[q_local * 128 + (d ^ l31)] = accO[dt][r];   // word-swz: conflict-free
        }
      if (hi == 0) SM_l[q_local] = l_r;
    }
    __syncthreads();                                  // partials visible
    if (g == 0) {
      float lo = SM_l[q_local];
      float inv = 1.0f / (l_r + lo);                  // l_r > 0 (diagonal in even group)
#pragma unroll
      for (int dt = 0; dt < 4; dt++)
#pragma unroll
        for (int q4 = 0; q4 < 4; q4++) {
          int dbase = 32 * dt + 8 * q4 + 4 * hi;
          u16x4 o;
#pragma unroll
          for (int j = 0; j < 4; j++) {
            int r = q4 * 4 + j, d = dbase + j;
            float vo = SM_acc[q_local * 128 + (d ^ l31)];
            o[j] = f2bf((accO[dt][r] + vo) * inv);
          }
          *(u16x4*)(ao + (size_t)q_row * HDIM + h * HD + dbase) = o;
        }
    }
  }
}

// ---------------- launch ----------------
extern "C" void kernel_launch(void* const* d_in, const int* in_sizes, int n_in,
                              void* d_out, int out_size, void* d_ws, size_t ws_size,
                              hipStream_t stream) {
  const float* x      = (const float*)d_in[0];
  const float* ve     = (const float*)d_in[1];
  const float* lam    = (const float*)d_in[2];
  const float* qkv_w  = (const float*)d_in[3];
  const float* proj_w = (const float*)d_in[4];
  float* out = (float*)d_out;

  char* p = (char*)d_ws;
  float* cosT = (float*)p;            p += (size_t)T_SEQ * 64 * 4;
  float* sinT = (float*)p;            p += (size_t)T_SEQ * 64 * 4;
  unsigned short* xb   = (unsigned short*)p; p += (size_t)T_SEQ * DIM * 2;
  unsigned short* wqb  = (unsigned short*)p; p += (size_t)3 * HDIM * DIM * 2;
  unsigned short* pwb  = (unsigned short*)p; p += (size_t)DIM * HDIM * 2;
  unsigned short* qkvb = (unsigned short*)p; p += (size_t)3 * NH * T_SEQ * HD * 2;
  unsigned short* vtb  = (unsigned short*)p; p += (size_t)NH * HD * T_SEQ * 2;
  unsigned short* aob  = (unsigned short*)p; p += (size_t)T_SEQ * HDIM * 2;

  // fused prep: x/qkv_w/proj_w converts + rope tables (boundaries 256-aligned)
  constexpr int PREP_N = T_SEQ * DIM / 4 + 3 * HDIM * DIM / 4 + DIM * HDIM / 4 + T_SEQ * 64;
  prep_all<<<PREP_N / 256, 256, 0, stream>>>(x, qkv_w, proj_w, xb, wqb, pwb, cosT, sinT);

  // QKV: 768 blocks = 3/CU exactly (R16 barrier-minimal BK=64 kernel)
  gemm256<0><<<768, 512, 0, stream>>>(xb, wqb, DIM, qkvb, nullptr, 3 * HDIM);
  // fused norm+rope (8192 blocks) + vmix-transpose (2048 blocks)
  norm_vmix<<<10240, 256, 0, stream>>>(qkvb, cosT, sinT, ve, lam, vtb);
  attn_fwd<<<256, 512, 0, stream>>>(qkvb, qkvb + (size_t)NH * T_SEQ * HD, vtb, aob);
  // proj: 256 blocks = 1/CU exactly
  gemm256<1><<<256, 512, 0, stream>>>(aob, pwb, HDIM, nullptr, out, HDIM);
}

// Round 20
// 281.126 us; speedup vs baseline: 1.1488x; 1.1026x over previous
//
#include <hip/hip_runtime.h>
#include <cstdint>
#include <cstddef>

// ---------------- constants ----------------
constexpr int T_SEQ = 4096;
constexpr int NH    = 16;
constexpr int HD    = 128;
constexpr int DIM   = 2048;
constexpr int HDIM  = 2048;   // NH*HD

typedef __attribute__((ext_vector_type(8)))  short  short8;
typedef __attribute__((ext_vector_type(4)))  float  f32x4;
typedef __attribute__((ext_vector_type(16))) float  f32x16;
typedef __attribute__((ext_vector_type(8)))  unsigned short u16x8;
typedef __attribute__((ext_vector_type(4)))  unsigned short u16x4;
typedef __attribute__((ext_vector_type(4)))  unsigned uint4v;
typedef __attribute__((ext_vector_type(2)))  int int2v;

__device__ __forceinline__ unsigned short f2bf(float f) {
  unsigned u = __float_as_uint(f);
  return (unsigned short)((u + 0x7FFFu + ((u >> 16) & 1u)) >> 16);  // RNE
}
__device__ __forceinline__ float bf2f(unsigned short h) {
  return __uint_as_float(((unsigned)h) << 16);
}
__device__ __forceinline__ void gload_lds16(const void* g, void* l) {
  __builtin_amdgcn_global_load_lds((const __attribute__((address_space(1))) void*)g,
                                   (__attribute__((address_space(3))) void*)l, 16, 0, 0);
}
__device__ __forceinline__ int2v plswap(int a, int b) {
  return __builtin_amdgcn_permlane32_swap(a, b, false, false);
}
__device__ __forceinline__ void bar() {           // raw barrier: no implicit vmcnt(0)
  asm volatile("" ::: "memory");
  __builtin_amdgcn_s_barrier();
  asm volatile("" ::: "memory");
}
#define VMCNT(n) asm volatile("s_waitcnt vmcnt(" #n ")" ::: "memory")

// ---------------- fused prep: 3x fp32->bf16 convert + RoPE tables, one launch ----------
__global__ __launch_bounds__(256) void prep_all(const float* __restrict__ x,
                                                const float* __restrict__ qkv_w,
                                                const float* __restrict__ proj_w,
                                                unsigned short* __restrict__ xb,
                                                unsigned short* __restrict__ wqb,
                                                unsigned short* __restrict__ pwb,
                                                float* __restrict__ cosT,
                                                float* __restrict__ sinT) {
  constexpr int N1 = T_SEQ * DIM / 4;              // 2,097,152
  constexpr int N2 = N1 + 3 * HDIM * DIM / 4;      // +3,145,728
  constexpr int N3 = N2 + DIM * HDIM / 4;          // +1,048,576
  int gid = blockIdx.x * 256 + threadIdx.x;
  const float* src; unsigned short* dst; int i4;
  if (gid < N1)      { src = x;      dst = xb;  i4 = gid; }
  else if (gid < N2) { src = qkv_w;  dst = wqb; i4 = gid - N1; }
  else if (gid < N3) { src = proj_w; dst = pwb; i4 = gid - N2; }
  else {
    int idx = gid - N3;                            // T_SEQ*64 entries
    int t = idx >> 6, i = idx & 63;
    float ang = (i < 32) ? exp2f(-10.0f * (float)i / 31.0f) : 0.0f;  // (1/1024)^(i/31)
    float th = (float)t * ang;
    cosT[idx] = cosf(th);
    sinT[idx] = sinf(th);
    return;
  }
  float4 v = ((const float4*)src)[i4];
  u16x4 o; o.x = f2bf(v.x); o.y = f2bf(v.y); o.z = f2bf(v.z); o.w = f2bf(v.w);
  ((u16x4*)dst)[i4] = o;
}

// ---------------- GEMM: C = A * B^T (deep-pipelined, T2+T3+T4+T5) ----------------
// Barrier-minimal K-loop (R16, best measured): only 2 load-bearing barriers/K-tile.
template <int MODE>
__global__ __launch_bounds__(512) void gemm256(const unsigned short* __restrict__ A,
                                               const unsigned short* __restrict__ B,
                                               int K, unsigned short* __restrict__ outb,
                                               float* __restrict__ outf, int N) {
  __shared__ __align__(16) char SM[3 * 49152];   // 144KB: 3 x [A 16KB | B 32KB]
  const int tid = threadIdx.x, w = tid >> 6, lane = tid & 63;
  const int wm = w >> 2, wn = w & 3;
  const int lr = lane >> 4, lc = lane & 15, lc7 = lc & 7;
  const int cpx = gridDim.x >> 3;
  const int idx = (blockIdx.x & 7) * cpx + (blockIdx.x >> 3);
  const int m0 = (idx & 31) * 128, n0 = (idx >> 5) * 256;

  const int arow = lane >> 3;
  const int xcol = ((lane & 7) ^ ((lane >> 3) & 7)) * 8;  // pre-swizzled source col

  auto stageA = [&](int buf, int t) {
    char* base = SM + buf * 49152;
#pragma unroll
    for (int i = 0; i < 2; i++) {
      int c = w + i * 8;
      gload_lds16(A + (size_t)(m0 + c * 8 + arow) * K + t * 64 + xcol, base + c * 1024);
    }
  };
  auto stageB0 = [&](int buf, int t) {
    char* base = SM + buf * 49152 + 16384;
    gload_lds16(B + (size_t)(n0 + w * 8 + arow) * K + t * 64 + xcol, base + w * 1024);
  };
  auto stageB1 = [&](int buf, int t) {
    char* base = SM + buf * 49152 + 16384;
#pragma unroll
    for (int i = 1; i < 4; i++) {
      int c = w + i * 8;
      gload_lds16(B + (size_t)(n0 + c * 8 + arow) * K + t * 64 + xcol, base + c * 1024);
    }
  };

  f32x4 acc[4][4] = {};
  const int NT = K >> 6;

  stageA(0, 0); stageB0(0, 0); stageB1(0, 0);
  stageA(1, 1); stageB0(1, 1); stageB1(1, 1);
  VMCNT(6);
  bar();

#pragma unroll 1
  for (int t = 0; t < NT; t++) {
    const int c = t % 3, s = (t + 2) % 3;
    const bool st = (t + 2) < NT;
    const char* Ab = SM + c * 49152;
    const char* Bb = Ab + 16384;

    short8 a[4], b[4];
#pragma unroll
    for (int mi = 0; mi < 4; mi++)
      a[mi] = *(const short8*)(Ab + (wm * 64 + mi * 16 + lc) * 128 + ((0 + lr) ^ lc7) * 16);
#pragma unroll
    for (int ni = 0; ni < 4; ni++)
      b[ni] = *(const short8*)(Bb + (wn * 64 + ni * 16 + lc) * 128 + ((0 + lr) ^ lc7) * 16);
    if (st) { stageA(s, t + 2); stageB0(s, t + 2); }
    __builtin_amdgcn_s_setprio(1);
#pragma unroll
    for (int mi = 0; mi < 4; mi++)
#pragma unroll
      for (int ni = 0; ni < 4; ni++)
        acc[mi][ni] = __builtin_amdgcn_mfma_f32_16x16x32_bf16(a[mi], b[ni], acc[mi][ni], 0, 0, 0);
    __builtin_amdgcn_s_setprio(0);

#pragma unroll
    for (int mi = 0; mi < 4; mi++)
      a[mi] = *(const short8*)(Ab + (wm * 64 + mi * 16 + lc) * 128 + ((4 + lr) ^ lc7) * 16);
#pragma unroll
    for (int ni = 0; ni < 4; ni++)
      b[ni] = *(const short8*)(Bb + (wn * 64 + ni * 16 + lc) * 128 + ((4 + lr) ^ lc7) * 16);
    if (st) stageB1(s, t + 2);
    if (st) { VMCNT(6); } else { VMCNT(0); }   // confirm tile t+1 (tail: drain)
    bar();                                     // (a) all waves' t+1 staging landed
    __builtin_amdgcn_s_setprio(1);
#pragma unroll
    for (int mi = 0; mi < 4; mi++)
#pragma unroll
      for (int ni = 0; ni < 4; ni++)
        acc[mi][ni] = __builtin_amdgcn_mfma_f32_16x16x32_bf16(a[mi], b[ni], acc[mi][ni], 0, 0, 0);
    __builtin_amdgcn_s_setprio(0);
    bar();                                     // (b) protect buf c vs t+1's stage
  }

#pragma unroll
  for (int mi = 0; mi < 4; mi++)
#pragma unroll
    for (int ni = 0; ni < 4; ni++)
#pragma unroll
      for (int r = 0; r < 4; r++) {
        int t = m0 + wm * 64 + mi * 16 + lr * 4 + r;
        int n = n0 + wn * 64 + ni * 16 + lc;
        float v = acc[mi][ni][r];
        if (MODE == 0) {
          int cc = n >> 11, e = n & 2047, h = e >> 7, d = e & 127;
          outb[(((size_t)cc * NH + h) * T_SEQ + t) * HD + d] = f2bf(v);
        } else {
          outf[(size_t)t * N + n] = v;
        }
      }
}

// ------- fused RMSNorm+RoPE (q,k -> FP8 e4m3) + vmix-transpose (v) -------
// Blocks 0..8191: norm+rope q,k rows; result written as OCP fp8 e4m3 to qk8
// (q pre-scaled by 1/sqrt(128)*log2e). q,k bf16 not written back (dead).
// Blocks 8192..10239: v' = l0*v + l1*ve transposed to vt[h][d][t].
__global__ __launch_bounds__(256) void norm_vmix(const unsigned short* __restrict__ qkvb,
                                                 const float* __restrict__ cosT,
                                                 const float* __restrict__ sinT,
                                                 const float* __restrict__ ve,
                                                 const float* __restrict__ lam,
                                                 unsigned short* __restrict__ vt,
                                                 unsigned char* __restrict__ qk8) {
  __shared__ float tile[64][65];
  const int bid = blockIdx.x, tid = threadIdx.x;

  if (bid < 8192) {
    const int li = tid & 15;                        // position within row (8 elems each)
    const int row = bid * 16 + (tid >> 4);          // row over [c][h][t], c in {0,1}
    const int t = row & (T_SEQ - 1);
    const unsigned short* rp = qkvb + (size_t)row * HD + li * 8;
    u16x8 raw = *(const u16x8*)rp;

    float v[8]; float ss = 0.0f;
#pragma unroll
    for (int j = 0; j < 8; j++) { v[j] = bf2f(raw[j]); ss += v[j] * v[j]; }
#pragma unroll
    for (int off = 1; off < 16; off <<= 1) ss += __shfl_xor(ss, off, 16);
    float rs = rsqrtf(ss * (1.0f / 128.0f) + 1e-6f);
    if (row < NH * T_SEQ) rs *= 0.088388347648318447f * 1.44269504f;  // q rows only

    uint4v rw = __builtin_bit_cast(uint4v, raw);
    uint4v pwv;
    pwv.x = (unsigned)__shfl_xor((int)rw.x, 8, 16);
    pwv.y = (unsigned)__shfl_xor((int)rw.y, 8, 16);
    pwv.z = (unsigned)__shfl_xor((int)rw.z, 8, 16);
    pwv.w = (unsigned)__shfl_xor((int)rw.w, 8, 16);
    u16x8 praw = __builtin_bit_cast(u16x8, pwv);
    float pv[8];
#pragma unroll
    for (int j = 0; j < 8; j++) pv[j] = bf2f(praw[j]);

    const int e0 = (li & 7) * 8;
    const bool hi8 = li >= 8;
    float4 c0 = *(const float4*)(cosT + t * 64 + e0);
    float4 c1 = *(const float4*)(cosT + t * 64 + e0 + 4);
    float4 s0 = *(const float4*)(sinT + t * 64 + e0);
    float4 s1 = *(const float4*)(sinT + t * 64 + e0 + 4);
    float cc[8] = {c0.x, c0.y, c0.z, c0.w, c1.x, c1.y, c1.z, c1.w};
    float sn[8] = {s0.x, s0.y, s0.z, s0.w, s1.x, s1.y, s1.z, s1.w};

    float rr[8];
#pragma unroll
    for (int j = 0; j < 8; j++) {
      float x1 = hi8 ? pv[j] : v[j];
      float x2 = hi8 ? v[j] : pv[j];
      float r = hi8 ? (-x1 * sn[j] + x2 * cc[j]) : (x1 * cc[j] + x2 * sn[j]);
      rr[j] = r * rs;
    }
    int w0 = 0, w1 = 0;
    w0 = __builtin_amdgcn_cvt_pk_fp8_f32(rr[0], rr[1], w0, false);
    w0 = __builtin_amdgcn_cvt_pk_fp8_f32(rr[2], rr[3], w0, true);
    w1 = __builtin_amdgcn_cvt_pk_fp8_f32(rr[4], rr[5], w1, false);
    w1 = __builtin_amdgcn_cvt_pk_fp8_f32(rr[6], rr[7], w1, true);
    int2v o8; o8.x = w0; o8.y = w1;
    *(int2v*)(qk8 + (size_t)row * HD + li * 8) = o8;
  } else {
    const int j2 = bid - 8192;                      // 0..2047
    const int t0 = (j2 & 63) * 64, d0 = ((j2 >> 6) & 1) * 64, h = j2 >> 7;
    const unsigned short* vb = qkvb + (size_t)2 * NH * T_SEQ * HD;
    const float l0 = lam[0], l1 = lam[1];
    const int tl = tid >> 4, dl4 = (tid & 15) * 4;
#pragma unroll
    for (int i = 0; i < 4; i++) {
      int t_local = tl + i * 16;
      int t = t0 + t_local;
      const unsigned short* vp = vb + ((size_t)h * T_SEQ + t) * HD + d0 + dl4;
      const float* vep = ve + (size_t)t * HDIM + h * HD + d0 + dl4;
      u16x4 vv = *(const u16x4*)vp;
      float4 vef = *(const float4*)vep;
      tile[t_local][dl4 + 0] = l0 * bf2f(vv.x) + l1 * vef.x;
      tile[t_local][dl4 + 1] = l0 * bf2f(vv.y) + l1 * vef.y;
      tile[t_local][dl4 + 2] = l0 * bf2f(vv.z) + l1 * vef.z;
      tile[t_local][dl4 + 3] = l0 * bf2f(vv.w) + l1 * vef.w;
    }
    __syncthreads();
#pragma unroll
    for (int i = 0; i < 2; i++) {
      int idx = tid + i * 256;
      int d_local = idx >> 3, tloc = (idx & 7) * 8;
      u16x8 o;
#pragma unroll
      for (int j = 0; j < 8; j++) o[j] = f2bf(tile[tloc + j][d_local]);
      *(u16x8*)(vt + ((size_t)h * HD + d0 + d_local) * T_SEQ + t0 + tloc) = o;
    }
  }
}

// ---------------- flash attention (causal): FP8 QK^T + bf16 PV, 32x32x16 ----------------
// R19 structure + FP8 Q/K: K LDS tile 16->8KB (group LDS traffic -25%; attn was
// ~83% LDS-BW-bound), K staging & Q regs halve. Fixed max FM=18.75 (fp8 norm
// inflation: 16.46 * 1.0625^2). K-row sigma permutation kept (lane-local PV).
// K swizzle for 128B rows: 16B slot' = dk ^ (row&7), b64 read at +8*hi.
__global__ __launch_bounds__(512)
__attribute__((amdgpu_waves_per_eu(2, 2)))
void attn_fwd(const unsigned char* __restrict__ q8,
              const unsigned char* __restrict__ k8,
              const unsigned short* __restrict__ vt,
              unsigned short* __restrict__ ao) {
  __shared__ __align__(16) char SMEM[98304];    // [group][ K 2x8KB | V 2x16KB ]
  __shared__ int gctr[2];                       // group-barrier monotonic counters
  const int bid = blockIdx.x;
  const int h  = (bid & 7) + ((bid >> 7) << 3);  // XCD swizzle: head h on XCD h%8
  const int pr = (bid >> 3) & 15;
  const int tid = threadIdx.x, w = tid >> 6, lane = tid & 63;
  const int g = w >> 2, wq = w & 3;
  const int l31 = lane & 31, hi = lane >> 5, r7 = l31 & 7;
  const unsigned char* qh = q8 + (size_t)h * T_SEQ * HD;
  const unsigned char* kh = k8 + (size_t)h * T_SEQ * HD;
  const unsigned short* vh = vt + (size_t)h * HD * T_SEQ;

  if (tid < 2) gctr[tid] = 0;
  __syncthreads();
  int bcnt = 0;
  auto GBAR = [&]() {   // group-local barrier: 4 waves of group g
    asm volatile("s_waitcnt lgkmcnt(0)" ::: "memory");
    ++bcnt;
    if (lane == 0)
      __hip_atomic_fetch_add(&gctr[g], 1, __ATOMIC_RELEASE, __HIP_MEMORY_SCOPE_WORKGROUP);
    while (__hip_atomic_load(&gctr[g], __ATOMIC_ACQUIRE, __HIP_MEMORY_SCOPE_WORKGROUP) < 4 * bcnt)
      __builtin_amdgcn_s_sleep(1);
  };

  char* Kbase = SMEM + g * 49152;               // 2 x 8KB
  char* Vbase = Kbase + 16384;                  // 2 x 16KB

  const int vcrow = lane >> 3, vslot0 = lane & 7;    // V staging: 8 rows / 1KB chunk

  auto STAGE = [&](int buf, int t) {                 // t = global kv tile index
    // K (fp8): 8KB tile = 8 chunks of 1KB (8 rows x 128B); 2 chunks/wave
#pragma unroll
    for (int i = 0; i < 2; i++) {
      int c = wq * 2 + i;
      int r = c * 8 + (lane >> 3);                   // LDS row position
      int rsrc = (r & ~12) | ((r & 4) << 1) | ((r & 8) >> 1);  // sigma: b2<->b3
      int sl = ((lane & 7) ^ (r & 7)) * 16;          // pre-swizzled source slot
      gload_lds16(kh + (size_t)(t * 64 + rsrc) * HD + sl,
                  Kbase + buf * 8192 + c * 1024);
    }
    // V (bf16): 16KB tile, 16 chunks; 4 chunks/wave
#pragma unroll
    for (int i = 0; i < 4; i++) {
      int vrow = (wq * 4 + i) * 8 + vcrow;
      int vcol = (vslot0 ^ (vrow & 7)) * 8;
      gload_lds16(vh + (size_t)vrow * T_SEQ + t * 64 + vcol,
                  Vbase + buf * 16384 + (wq * 4 + i) * 1024);
    }
  };

  const float FM = 18.75f;   // fixed softmax max (exp2 domain) incl. fp8 norm inflation

#pragma unroll 1
  for (int which = 0; which < 2; ++which) {
    const int qt = which ? pr : (31 - pr);     // heavy tile first
    const int ng = qt + 1;                     // tiles for THIS group (parity g)
    const int q_row = qt * 128 + wq * 32 + l31;

    long qf8[8];                               // B-frag: Q[q_row][16dk + 8hi + 0..7] fp8
#pragma unroll
    for (int dk = 0; dk < 8; dk++)
      qf8[dk] = *(const long*)(qh + (size_t)q_row * HD + dk * 16 + hi * 8);

    f32x16 accO[4] = {};                       // O^T: col=q, rows d (4 tiles of 32)
    float l_r = 0.0f;

    __syncthreads();                           // prev combine reads done (cross-group)
    STAGE(0, g);

#pragma unroll 1
    for (int it = 0; it < ng; it++) {
      const int t = 2 * it + g;                // this group's kv tile
      const int cur = it & 1;
      asm volatile("s_waitcnt vmcnt(0)" ::: "memory");  // own stage(cur) landed
      GBAR();                                           // group's stage(cur) landed
      if (it + 1 < ng) STAGE(cur ^ 1, t + 2);           // prefetch under compute

      // ---- S^T = K Q^T : 2 kv-subtiles x 8 d-steps (fp8 x fp8 -> f32) ----
      f32x16 accS0 = {}, accS1 = {};
      const char* Kb = Kbase + cur * 8192;
      __builtin_amdgcn_s_setprio(1);
#pragma unroll
      for (int dk = 0; dk < 8; dk++) {
        int off = l31 * 128 + ((dk ^ r7) * 16) + hi * 8;
        long k0 = *(const long*)(Kb + off);
        long k1 = *(const long*)(Kb + 32 * 128 + off);
        accS0 = __builtin_amdgcn_mfma_f32_32x32x16_fp8_fp8(k0, qf8[dk], accS0, 0, 0, 0);
        accS1 = __builtin_amdgcn_mfma_f32_32x32x16_fp8_fp8(k1, qf8[dk], accS1, 0, 0, 0);
      }
      __builtin_amdgcn_s_setprio(0);

      // ---- causal mask + exp2(s - FM); permuted layout: kv = 64t+(r&7)+8hi+16(r>>3) ----
      float p[32];
      const bool need_mask = (t * 64 + 63) > (qt * 128 + wq * 32);
      if (need_mask) {
#pragma unroll
        for (int r = 0; r < 16; r++) {
          int kv0 = t * 64 + (r & 7) + 8 * hi + 16 * (r >> 3);
          p[r]      = (kv0      > q_row) ? 0.0f : exp2f(accS0[r] - FM);
          p[16 + r] = (kv0 + 32 > q_row) ? 0.0f : exp2f(accS1[r] - FM);
        }
      } else {
#pragma unroll
        for (int r = 0; r < 16; r++) {
          p[r]      = exp2f(accS0[r] - FM);
          p[16 + r] = exp2f(accS1[r] - FM);
        }
      }

      // ---- row sum (partner holds complementary kv set; one cross-half swap) ----
      float s16[16];
#pragma unroll
      for (int i = 0; i < 16; i++) s16[i] = p[i] + p[i + 16];
#pragma unroll
      for (int st = 8; st >= 1; st >>= 1)
#pragma unroll
        for (int i = 0; i < st; i++) s16[i] += s16[i + st];
      int2v sr_ = plswap(__float_as_int(s16[0]), __float_as_int(s16[0]));
      l_r += s16[0] + __int_as_float(hi ? sr_.x : sr_.y);

      // ---- PV: O^T += V^T P^T ; pb[ks] = p[8ks..8ks+7] (lane-local, no exchange) ----
      const char* Vb = Vbase + cur * 16384 + l31 * 128;
#pragma unroll
      for (int ks = 0; ks < 4; ks++) {
        uint4v pw;
#pragma unroll
        for (int w2 = 0; w2 < 4; w2++) {
          unsigned pk_;
          asm("v_cvt_pk_bf16_f32 %0, %1, %2"
              : "=v"(pk_) : "v"(p[8 * ks + 2 * w2]), "v"(p[8 * ks + 2 * w2 + 1]));
          pw[w2] = pk_;
        }
        short8 pb = __builtin_bit_cast(short8, pw);
        int sl = ((2 * ks + hi) ^ r7) * 16;
        __builtin_amdgcn_s_setprio(1);
#pragma unroll
        for (int dt = 0; dt < 4; dt++) {
          short8 vf = *(const short8*)(Vb + dt * 32 * 128 + sl);
          accO[dt] = __builtin_amdgcn_mfma_f32_32x32x16_bf16(vf, pb, accO[dt], 0, 0, 0);
        }
        __builtin_amdgcn_s_setprio(0);
      }
    }

    // ---- combine even/odd partials (fixed max -> merge is a plain sum) ----
    __syncthreads();                                  // all compute done (cross-group)
    float* SM_acc = (float*)(SMEM + 32768);           // 64KB staging (dead post-compute)
    float* SM_l   = (float*)SMEM;                     // 512B (dead post-compute)
    const int q_local = wq * 32 + l31;
    if (g == 1) {
#pragma unroll
      for (int dt = 0; dt < 4; dt++)
#pragma unroll
        for (int r = 0; r < 16; r++) {
          int d = 32 * dt + (r & 3) + 8 * (r >> 2) + 4 * hi;
          SM_acc[q_local * 128 + (d ^ l31)] = accO[dt][r];   // word-swz: conflict-free
        }
      if (hi == 0) SM_l[q_local] = l_r;
    }
    __syncthreads();                                  // partials visible
    if (g == 0) {
      float lo = SM_l[q_local];
      float inv = 1.0f / (l_r + lo);                  // l_r > 0 (diagonal in even group)
#pragma unroll
      for (int dt = 0; dt < 4; dt++)
#pragma unroll
        for (int q4 = 0; q4 < 4; q4++) {
          int dbase = 32 * dt + 8 * q4 + 4 * hi;
          u16x4 o;
#pragma unroll
          for (int j = 0; j < 4; j++) {
            int r = q4 * 4 + j, d = dbase + j;
            float vo = SM_acc[q_local * 128 + (d ^ l31)];
            o[j] = f2bf((accO[dt][r] + vo) * inv);
          }
          *(u16x4*)(ao + (size_t)q_row * HDIM + h * HD + dbase) = o;
        }
    }
  }
}

// ---------------- launch ----------------
extern "C" void kernel_launch(void* const* d_in, const int* in_sizes, int n_in,
                              void* d_out, int out_size, void* d_ws, size_t ws_size,
                              hipStream_t stream) {
  const float* x      = (const float*)d_in[0];
  const float* ve     = (const float*)d_in[1];
  const float* lam    = (const float*)d_in[2];
  const float* qkv_w  = (const float*)d_in[3];
  const float* proj_w = (const float*)d_in[4];
  float* out = (float*)d_out;

  char* p = (char*)d_ws;
  float* cosT = (float*)p;            p += (size_t)T_SEQ * 64 * 4;
  float* sinT = (float*)p;            p += (size_t)T_SEQ * 64 * 4;
  unsigned short* xb   = (unsigned short*)p; p += (size_t)T_SEQ * DIM * 2;
  unsigned short* wqb  = (unsigned short*)p; p += (size_t)3 * HDIM * DIM * 2;
  unsigned short* pwb  = (unsigned short*)p; p += (size_t)DIM * HDIM * 2;
  unsigned short* qkvb = (unsigned short*)p; p += (size_t)3 * NH * T_SEQ * HD * 2;
  unsigned short* vtb  = (unsigned short*)p; p += (size_t)NH * HD * T_SEQ * 2;
  unsigned short* aob  = (unsigned short*)p; p += (size_t)T_SEQ * HDIM * 2;
  unsigned char*  qk8  = (unsigned char*)p;  p += (size_t)2 * NH * T_SEQ * HD;

  // fused prep: x/qkv_w/proj_w converts + rope tables (boundaries 256-aligned)
  constexpr int PREP_N = T_SEQ * DIM / 4 + 3 * HDIM * DIM / 4 + DIM * HDIM / 4 + T_SEQ * 64;
  prep_all<<<PREP_N / 256, 256, 0, stream>>>(x, qkv_w, proj_w, xb, wqb, pwb, cosT, sinT);

  // QKV: 768 blocks = 3/CU exactly (R16 barrier-minimal BK=64 kernel)
  gemm256<0><<<768, 512, 0, stream>>>(xb, wqb, DIM, qkvb, nullptr, 3 * HDIM);
  // fused norm+rope->fp8 (8192 blocks) + vmix-transpose (2048 blocks)
  norm_vmix<<<10240, 256, 0, stream>>>(qkvb, cosT, sinT, ve, lam, vtb, qk8);
  attn_fwd<<<256, 512, 0, stream>>>(qk8, qk8 + (size_t)NH * T_SEQ * HD, vtb, aob);
  // proj: 256 blocks = 1/CU exactly
  gemm256<1><<<256, 512, 0, stream>>>(aob, pwb, HDIM, nullptr, out, HDIM);
}

// Round 21
// 280.447 us; speedup vs baseline: 1.1515x; 1.0024x over previous
//
#include <hip/hip_runtime.h>
#include <cstdint>
#include <cstddef>

// ---------------- constants ----------------
constexpr int T_SEQ = 4096;
constexpr int NH    = 16;
constexpr int HD    = 128;
constexpr int DIM   = 2048;
constexpr int HDIM  = 2048;   // NH*HD

typedef __attribute__((ext_vector_type(8)))  short  short8;
typedef __attribute__((ext_vector_type(4)))  float  f32x4;
typedef __attribute__((ext_vector_type(16))) float  f32x16;
typedef __attribute__((ext_vector_type(8)))  unsigned short u16x8;
typedef __attribute__((ext_vector_type(4)))  unsigned short u16x4;
typedef __attribute__((ext_vector_type(4)))  unsigned uint4v;
typedef __attribute__((ext_vector_type(2)))  int int2v;

__device__ __forceinline__ unsigned short f2bf(float f) {
  unsigned u = __float_as_uint(f);
  return (unsigned short)((u + 0x7FFFu + ((u >> 16) & 1u)) >> 16);  // RNE
}
__device__ __forceinline__ float bf2f(unsigned short h) {
  return __uint_as_float(((unsigned)h) << 16);
}
__device__ __forceinline__ void gload_lds16(const void* g, void* l) {
  __builtin_amdgcn_global_load_lds((const __attribute__((address_space(1))) void*)g,
                                   (__attribute__((address_space(3))) void*)l, 16, 0, 0);
}
__device__ __forceinline__ int2v plswap(int a, int b) {
  return __builtin_amdgcn_permlane32_swap(a, b, false, false);
}
__device__ __forceinline__ void bar() {           // raw barrier: no implicit vmcnt(0)
  asm volatile("" ::: "memory");
  __builtin_amdgcn_s_barrier();
  asm volatile("" ::: "memory");
}
#define VMCNT(n) asm volatile("s_waitcnt vmcnt(" #n ")" ::: "memory")

// ---------------- fused prep: 3x fp32->bf16 convert + RoPE tables, one launch ----------
__global__ __launch_bounds__(256) void prep_all(const float* __restrict__ x,
                                                const float* __restrict__ qkv_w,
                                                const float* __restrict__ proj_w,
                                                unsigned short* __restrict__ xb,
                                                unsigned short* __restrict__ wqb,
                                                unsigned short* __restrict__ pwb,
                                                float* __restrict__ cosT,
                                                float* __restrict__ sinT) {
  constexpr int N1 = T_SEQ * DIM / 4;              // 2,097,152
  constexpr int N2 = N1 + 3 * HDIM * DIM / 4;      // +3,145,728
  constexpr int N3 = N2 + DIM * HDIM / 4;          // +1,048,576
  int gid = blockIdx.x * 256 + threadIdx.x;
  const float* src; unsigned short* dst; int i4;
  if (gid < N1)      { src = x;      dst = xb;  i4 = gid; }
  else if (gid < N2) { src = qkv_w;  dst = wqb; i4 = gid - N1; }
  else if (gid < N3) { src = proj_w; dst = pwb; i4 = gid - N2; }
  else {
    int idx = gid - N3;                            // T_SEQ*64 entries
    int t = idx >> 6, i = idx & 63;
    float ang = (i < 32) ? exp2f(-10.0f * (float)i / 31.0f) : 0.0f;  // (1/1024)^(i/31)
    float th = (float)t * ang;
    cosT[idx] = cosf(th);
    sinT[idx] = sinf(th);
    return;
  }
  float4 v = ((const float4*)src)[i4];
  u16x4 o; o.x = f2bf(v.x); o.y = f2bf(v.y); o.z = f2bf(v.z); o.w = f2bf(v.w);
  ((u16x4*)dst)[i4] = o;
}

// ---------------- GEMM: C = A * B^T (deep-pipelined, T2+T3+T4+T5) ----------------
// Barrier-minimal K-loop (R16, best measured): only 2 load-bearing barriers/K-tile.
template <int MODE>
__global__ __launch_bounds__(512) void gemm256(const unsigned short* __restrict__ A,
                                               const unsigned short* __restrict__ B,
                                               int K, unsigned short* __restrict__ outb,
                                               float* __restrict__ outf, int N) {
  __shared__ __align__(16) char SM[3 * 49152];   // 144KB: 3 x [A 16KB | B 32KB]
  const int tid = threadIdx.x, w = tid >> 6, lane = tid & 63;
  const int wm = w >> 2, wn = w & 3;
  const int lr = lane >> 4, lc = lane & 15, lc7 = lc & 7;
  const int cpx = gridDim.x >> 3;
  const int idx = (blockIdx.x & 7) * cpx + (blockIdx.x >> 3);
  const int m0 = (idx & 31) * 128, n0 = (idx >> 5) * 256;

  const int arow = lane >> 3;
  const int xcol = ((lane & 7) ^ ((lane >> 3) & 7)) * 8;  // pre-swizzled source col

  auto stageA = [&](int buf, int t) {
    char* base = SM + buf * 49152;
#pragma unroll
    for (int i = 0; i < 2; i++) {
      int c = w + i * 8;
      gload_lds16(A + (size_t)(m0 + c * 8 + arow) * K + t * 64 + xcol, base + c * 1024);
    }
  };
  auto stageB0 = [&](int buf, int t) {
    char* base = SM + buf * 49152 + 16384;
    gload_lds16(B + (size_t)(n0 + w * 8 + arow) * K + t * 64 + xcol, base + w * 1024);
  };
  auto stageB1 = [&](int buf, int t) {
    char* base = SM + buf * 49152 + 16384;
#pragma unroll
    for (int i = 1; i < 4; i++) {
      int c = w + i * 8;
      gload_lds16(B + (size_t)(n0 + c * 8 + arow) * K + t * 64 + xcol, base + c * 1024);
    }
  };

  f32x4 acc[4][4] = {};
  const int NT = K >> 6;

  stageA(0, 0); stageB0(0, 0); stageB1(0, 0);
  stageA(1, 1); stageB0(1, 1); stageB1(1, 1);
  VMCNT(6);
  bar();

#pragma unroll 1
  for (int t = 0; t < NT; t++) {
    const int c = t % 3, s = (t + 2) % 3;
    const bool st = (t + 2) < NT;
    const char* Ab = SM + c * 49152;
    const char* Bb = Ab + 16384;

    short8 a[4], b[4];
#pragma unroll
    for (int mi = 0; mi < 4; mi++)
      a[mi] = *(const short8*)(Ab + (wm * 64 + mi * 16 + lc) * 128 + ((0 + lr) ^ lc7) * 16);
#pragma unroll
    for (int ni = 0; ni < 4; ni++)
      b[ni] = *(const short8*)(Bb + (wn * 64 + ni * 16 + lc) * 128 + ((0 + lr) ^ lc7) * 16);
    if (st) { stageA(s, t + 2); stageB0(s, t + 2); }
    __builtin_amdgcn_s_setprio(1);
#pragma unroll
    for (int mi = 0; mi < 4; mi++)
#pragma unroll
      for (int ni = 0; ni < 4; ni++)
        acc[mi][ni] = __builtin_amdgcn_mfma_f32_16x16x32_bf16(a[mi], b[ni], acc[mi][ni], 0, 0, 0);
    __builtin_amdgcn_s_setprio(0);

#pragma unroll
    for (int mi = 0; mi < 4; mi++)
      a[mi] = *(const short8*)(Ab + (wm * 64 + mi * 16 + lc) * 128 + ((4 + lr) ^ lc7) * 16);
#pragma unroll
    for (int ni = 0; ni < 4; ni++)
      b[ni] = *(const short8*)(Bb + (wn * 64 + ni * 16 + lc) * 128 + ((4 + lr) ^ lc7) * 16);
    if (st) stageB1(s, t + 2);
    if (st) { VMCNT(6); } else { VMCNT(0); }   // confirm tile t+1 (tail: drain)
    bar();                                     // (a) all waves' t+1 staging landed
    __builtin_amdgcn_s_setprio(1);
#pragma unroll
    for (int mi = 0; mi < 4; mi++)
#pragma unroll
      for (int ni = 0; ni < 4; ni++)
        acc[mi][ni] = __builtin_amdgcn_mfma_f32_16x16x32_bf16(a[mi], b[ni], acc[mi][ni], 0, 0, 0);
    __builtin_amdgcn_s_setprio(0);
    bar();                                     // (b) protect buf c vs t+1's stage
  }

#pragma unroll
  for (int mi = 0; mi < 4; mi++)
#pragma unroll
    for (int ni = 0; ni < 4; ni++)
#pragma unroll
      for (int r = 0; r < 4; r++) {
        int t = m0 + wm * 64 + mi * 16 + lr * 4 + r;
        int n = n0 + wn * 64 + ni * 16 + lc;
        float v = acc[mi][ni][r];
        if (MODE == 0) {
          int cc = n >> 11, e = n & 2047, h = e >> 7, d = e & 127;
          outb[(((size_t)cc * NH + h) * T_SEQ + t) * HD + d] = f2bf(v);
        } else {
          outf[(size_t)t * N + n] = v;
        }
      }
}

// ------- fused RMSNorm+RoPE (q,k -> FP8 e4m3) + vmix-transpose (v) -------
__global__ __launch_bounds__(256) void norm_vmix(const unsigned short* __restrict__ qkvb,
                                                 const float* __restrict__ cosT,
                                                 const float* __restrict__ sinT,
                                                 const float* __restrict__ ve,
                                                 const float* __restrict__ lam,
                                                 unsigned short* __restrict__ vt,
                                                 unsigned char* __restrict__ qk8) {
  __shared__ float tile[64][65];
  const int bid = blockIdx.x, tid = threadIdx.x;

  if (bid < 8192) {
    const int li = tid & 15;                        // position within row (8 elems each)
    const int row = bid * 16 + (tid >> 4);          // row over [c][h][t], c in {0,1}
    const int t = row & (T_SEQ - 1);
    const unsigned short* rp = qkvb + (size_t)row * HD + li * 8;
    u16x8 raw = *(const u16x8*)rp;

    float v[8]; float ss = 0.0f;
#pragma unroll
    for (int j = 0; j < 8; j++) { v[j] = bf2f(raw[j]); ss += v[j] * v[j]; }
#pragma unroll
    for (int off = 1; off < 16; off <<= 1) ss += __shfl_xor(ss, off, 16);
    float rs = rsqrtf(ss * (1.0f / 128.0f) + 1e-6f);
    if (row < NH * T_SEQ) rs *= 0.088388347648318447f * 1.44269504f;  // q rows only

    uint4v rw = __builtin_bit_cast(uint4v, raw);
    uint4v pwv;
    pwv.x = (unsigned)__shfl_xor((int)rw.x, 8, 16);
    pwv.y = (unsigned)__shfl_xor((int)rw.y, 8, 16);
    pwv.z = (unsigned)__shfl_xor((int)rw.z, 8, 16);
    pwv.w = (unsigned)__shfl_xor((int)rw.w, 8, 16);
    u16x8 praw = __builtin_bit_cast(u16x8, pwv);
    float pv[8];
#pragma unroll
    for (int j = 0; j < 8; j++) pv[j] = bf2f(praw[j]);

    const int e0 = (li & 7) * 8;
    const bool hi8 = li >= 8;
    float4 c0 = *(const float4*)(cosT + t * 64 + e0);
    float4 c1 = *(const float4*)(cosT + t * 64 + e0 + 4);
    float4 s0 = *(const float4*)(sinT + t * 64 + e0);
    float4 s1 = *(const float4*)(sinT + t * 64 + e0 + 4);
    float cc[8] = {c0.x, c0.y, c0.z, c0.w, c1.x, c1.y, c1.z, c1.w};
    float sn[8] = {s0.x, s0.y, s0.z, s0.w, s1.x, s1.y, s1.z, s1.w};

    float rr[8];
#pragma unroll
    for (int j = 0; j < 8; j++) {
      float x1 = hi8 ? pv[j] : v[j];
      float x2 = hi8 ? v[j] : pv[j];
      float r = hi8 ? (-x1 * sn[j] + x2 * cc[j]) : (x1 * cc[j] + x2 * sn[j]);
      rr[j] = r * rs;
    }
    int w0 = 0, w1 = 0;
    w0 = __builtin_amdgcn_cvt_pk_fp8_f32(rr[0], rr[1], w0, false);
    w0 = __builtin_amdgcn_cvt_pk_fp8_f32(rr[2], rr[3], w0, true);
    w1 = __builtin_amdgcn_cvt_pk_fp8_f32(rr[4], rr[5], w1, false);
    w1 = __builtin_amdgcn_cvt_pk_fp8_f32(rr[6], rr[7], w1, true);
    int2v o8; o8.x = w0; o8.y = w1;
    *(int2v*)(qk8 + (size_t)row * HD + li * 8) = o8;
  } else {
    const int j2 = bid - 8192;                      // 0..2047
    const int t0 = (j2 & 63) * 64, d0 = ((j2 >> 6) & 1) * 64, h = j2 >> 7;
    const unsigned short* vb = qkvb + (size_t)2 * NH * T_SEQ * HD;
    const float l0 = lam[0], l1 = lam[1];
    const int tl = tid >> 4, dl4 = (tid & 15) * 4;
#pragma unroll
    for (int i = 0; i < 4; i++) {
      int t_local = tl + i * 16;
      int t = t0 + t_local;
      const unsigned short* vp = vb + ((size_t)h * T_SEQ + t) * HD + d0 + dl4;
      const float* vep = ve + (size_t)t * HDIM + h * HD + d0 + dl4;
      u16x4 vv = *(const u16x4*)vp;
      float4 vef = *(const float4*)vep;
      tile[t_local][dl4 + 0] = l0 * bf2f(vv.x) + l1 * vef.x;
      tile[t_local][dl4 + 1] = l0 * bf2f(vv.y) + l1 * vef.y;
      tile[t_local][dl4 + 2] = l0 * bf2f(vv.z) + l1 * vef.z;
      tile[t_local][dl4 + 3] = l0 * bf2f(vv.w) + l1 * vef.w;
    }
    __syncthreads();
#pragma unroll
    for (int i = 0; i < 2; i++) {
      int idx = tid + i * 256;
      int d_local = idx >> 3, tloc = (idx & 7) * 8;
      u16x8 o;
#pragma unroll
      for (int j = 0; j < 8; j++) o[j] = f2bf(tile[tloc + j][d_local]);
      *(u16x8*)(vt + ((size_t)h * HD + d0 + d_local) * T_SEQ + t0 + tloc) = o;
    }
  }
}

// ---------------- flash attention (causal): FP8 QK^T + bf16 PV, KVBLK=128 ----------------
// R20 math (fp8 QK, FM=18.75, sigma K-row permutation, lane-local PV) with 128-kv tiles
// processed as two 64-kv substeps: halves per-iter fixed overhead (vmcnt drain, GBAR
// round-trips, stage batches, chain warmups) -- attn was ~85% stall at R20's 64-kv iters.
// LDS/group: K fp8 dbuf 2x16KB + V bf16 single-buffered 32KB = 64KB (128KB total).
// V single-buffer sync: stage V(t) after GBAR-top (all prev V reads retired);
// vmcnt(4)+GBAR before first PV (V landed everywhere, K(t+2) stays in flight).
__global__ __launch_bounds__(512)
__attribute__((amdgpu_waves_per_eu(2, 2)))
void attn_fwd(const unsigned char* __restrict__ q8,
              const unsigned char* __restrict__ k8,
              const unsigned short* __restrict__ vt,
              unsigned short* __restrict__ ao) {
  __shared__ __align__(16) char SMEM[131072];   // [group][ K 2x16KB | V 32KB ]
  __shared__ int gctr[2];                       // group-barrier monotonic counters
  const int bid = blockIdx.x;
  const int h  = (bid & 7) + ((bid >> 7) << 3);  // XCD swizzle: head h on XCD h%8
  const int pr = (bid >> 3) & 15;
  const int tid = threadIdx.x, w = tid >> 6, lane = tid & 63;
  const int g = w >> 2, wq = w & 3;
  const int l31 = lane & 31, hi = lane >> 5, r7 = l31 & 7;
  const unsigned char* qh = q8 + (size_t)h * T_SEQ * HD;
  const unsigned char* kh = k8 + (size_t)h * T_SEQ * HD;
  const unsigned short* vh = vt + (size_t)h * HD * T_SEQ;

  if (tid < 2) gctr[tid] = 0;
  __syncthreads();
  int bcnt = 0;
  auto GBAR = [&]() {   // group-local barrier: 4 waves of group g
    asm volatile("s_waitcnt lgkmcnt(0)" ::: "memory");
    ++bcnt;
    if (lane == 0)
      __hip_atomic_fetch_add(&gctr[g], 1, __ATOMIC_RELEASE, __HIP_MEMORY_SCOPE_WORKGROUP);
    while (__hip_atomic_load(&gctr[g], __ATOMIC_ACQUIRE, __HIP_MEMORY_SCOPE_WORKGROUP) < 4 * bcnt)
      __builtin_amdgcn_s_sleep(1);
  };

  char* Kbase = SMEM + g * 65536;               // 2 x 16KB
  char* Vbase = Kbase + 32768;                  // 32KB single buffer

  auto STAGE_K = [&](int buf, int t) {          // t = 128-kv tile index
#pragma unroll
    for (int i = 0; i < 4; i++) {
      int c = wq * 4 + i;                       // 16 chunks of 1KB (8 rows x 128B)
      int r = c * 8 + (lane >> 3);              // LDS row position 0..127
      int rsrc = (r & ~12) | ((r & 4) << 1) | ((r & 8) >> 1);  // sigma: b2<->b3
      int sl = ((lane & 7) ^ (r & 7)) * 16;     // pre-swizzled source slot
      gload_lds16(kh + (size_t)(t * 128 + rsrc) * HD + sl,
                  Kbase + buf * 16384 + c * 1024);
    }
  };
  auto STAGE_V = [&](int t) {                   // 32 chunks of 1KB (4 rows x 256B)
#pragma unroll
    for (int i = 0; i < 8; i++) {
      int c = wq * 8 + i;
      int vrow = c * 4 + (lane >> 4);           // d row 0..127
      int j = (lane & 15) ^ (vrow & 15);        // pre-swizzled 16B granule
      gload_lds16(vh + (size_t)vrow * T_SEQ + t * 128 + j * 8,
                  Vbase + c * 1024);
    }
  };

  const float FM = 18.75f;   // fixed softmax max (exp2 domain) incl. fp8 norm inflation
  const int dmask = l31 & 15;

#pragma unroll 1
  for (int which = 0; which < 2; ++which) {
    const int qt = which ? pr : (31 - pr);     // heavy q-tile first (128-row tiles)
    const int ng = (qt >= g) ? (((qt - g) >> 1) + 1) : 0;  // tiles t==g (mod 2), t<=qt
    const int q_row = qt * 128 + wq * 32 + l31;

    long qf8[8];                               // B-frag: Q[q_row][16dk + 8hi + 0..7] fp8
#pragma unroll
    for (int dk = 0; dk < 8; dk++)
      qf8[dk] = *(const long*)(qh + (size_t)q_row * HD + dk * 16 + hi * 8);

    f32x16 accO[4] = {};                       // O^T: col=q, rows d (4 tiles of 32)
    float l_r = 0.0f;

    __syncthreads();                           // prev combine reads done (cross-group)
    if (ng > 0) STAGE_K(0, g);

#pragma unroll 1
    for (int it = 0; it < ng; it++) {
      const int t = 2 * it + g;                // this group's 128-kv tile
      const int cur = it & 1;
      VMCNT(0);                                // K(t) landed (only outstanding)
      GBAR();                                  // all: K landed + prev V reads retired
      STAGE_V(t);                              // single-buffer V for this tile
      if (it + 1 < ng) STAGE_K(cur ^ 1, t + 2);
      const char* Kb = Kbase + cur * 16384;
      const bool diag = (t == qt);

#pragma unroll
      for (int s = 0; s < 2; s++) {            // two 64-kv substeps
        // ---- S^T = K Q^T (fp8) : 2 x 32-kv blocks x 8 d-steps ----
        f32x16 accS0 = {}, accS1 = {};
        const char* Ks = Kb + s * 8192;
        __builtin_amdgcn_s_setprio(1);
#pragma unroll
        for (int dk = 0; dk < 8; dk++) {
          int off = l31 * 128 + ((dk ^ r7) * 16) + hi * 8;
          long k0 = *(const long*)(Ks + off);
          long k1 = *(const long*)(Ks + 4096 + off);
          accS0 = __builtin_amdgcn_mfma_f32_32x32x16_fp8_fp8(k0, qf8[dk], accS0, 0, 0, 0);
          accS1 = __builtin_amdgcn_mfma_f32_32x32x16_fp8_fp8(k1, qf8[dk], accS1, 0, 0, 0);
        }
        __builtin_amdgcn_s_setprio(0);

        // ---- mask + exp2(s - FM); kv = 128t + 64s + 32b + (r&7)+8hi+16(r>>3) ----
        float p[32];
        if (diag) {
#pragma unroll
          for (int r = 0; r < 16; r++) {
            int kv0 = t * 128 + s * 64 + (r & 7) + 8 * hi + 16 * (r >> 3);
            p[r]      = (kv0      > q_row) ? 0.0f : exp2f(accS0[r] - FM);
            p[16 + r] = (kv0 + 32 > q_row) ? 0.0f : exp2f(accS1[r] - FM);
          }
        } else {
#pragma unroll
          for (int r = 0; r < 16; r++) {
            p[r]      = exp2f(accS0[r] - FM);
            p[16 + r] = exp2f(accS1[r] - FM);
          }
        }

        // ---- row sum ----
        float s16[16];
#pragma unroll
        for (int i = 0; i < 16; i++) s16[i] = p[i] + p[i + 16];
#pragma unroll
        for (int st = 8; st >= 1; st >>= 1)
#pragma unroll
          for (int i = 0; i < st; i++) s16[i] += s16[i + st];
        int2v sr_ = plswap(__float_as_int(s16[0]), __float_as_int(s16[0]));
        l_r += s16[0] + __int_as_float(hi ? sr_.x : sr_.y);

        // ---- V(t) landed? (once, before first PV of this tile) ----
        if (s == 0) {
          if (it + 1 < ng) { VMCNT(4); } else { VMCNT(0); }  // K(t+2) stays in flight
          GBAR();                                            // all waves' V slices in
        }

        // ---- PV: O^T += V^T P^T ; pb[ks] = p[8ks..8ks+7] (lane-local) ----
#pragma unroll
        for (int ks = 0; ks < 4; ks++) {
          uint4v pw;
#pragma unroll
          for (int w2 = 0; w2 < 4; w2++) {
            unsigned pk_;
            asm("v_cvt_pk_bf16_f32 %0, %1, %2"
                : "=v"(pk_) : "v"(p[8 * ks + 2 * w2]), "v"(p[8 * ks + 2 * w2 + 1]));
            pw[w2] = pk_;
          }
          short8 pb = __builtin_bit_cast(short8, pw);
          int slot = (8 * s + 2 * ks + hi) ^ dmask;
          __builtin_amdgcn_s_setprio(1);
#pragma unroll
          for (int dt = 0; dt < 4; dt++) {
            short8 vf = *(const short8*)(Vbase + (dt * 32 + l31) * 256 + slot * 16);
            accO[dt] = __builtin_amdgcn_mfma_f32_32x32x16_bf16(vf, pb, accO[dt], 0, 0, 0);
          }
          __builtin_amdgcn_s_setprio(0);
        }
      }
    }

    // ---- combine even/odd partials (fixed max -> merge is a plain sum) ----
    __syncthreads();                                  // all compute done (cross-group)
    float* SM_acc = (float*)(SMEM + 65536);           // group-1 region (dead now), 64KB
    float* SM_l   = (float*)SMEM;                     // group-0 region (dead now)
    const int q_local = wq * 32 + l31;
    if (g == 1) {
#pragma unroll
      for (int dt = 0; dt < 4; dt++)
#pragma unroll
        for (int r = 0; r < 16; r++) {
          int d = 32 * dt + (r & 3) + 8 * (r >> 2) + 4 * hi;
          SM_acc[q_local * 128 + (d ^ l31)] = accO[dt][r];   // word-swz: conflict-free
        }
      if (hi == 0) SM_l[q_local] = l_r;
    }
    __syncthreads();                                  // partials visible
    if (g == 0) {
      float lo = SM_l[q_local];
      float inv = 1.0f / (l_r + lo);                  // l_r > 0 (tile 0 in even group)
#pragma unroll
      for (int dt = 0; dt < 4; dt++)
#pragma unroll
        for (int q4 = 0; q4 < 4; q4++) {
          int dbase = 32 * dt + 8 * q4 + 4 * hi;
          u16x4 o;
#pragma unroll
          for (int j = 0; j < 4; j++) {
            int r = q4 * 4 + j, d = dbase + j;
            float vo = SM_acc[q_local * 128 + (d ^ l31)];
            o[j] = f2bf((accO[dt][r] + vo) * inv);
          }
          *(u16x4*)(ao + (size_t)q_row * HDIM + h * HD + dbase) = o;
        }
    }
  }
}

// ---------------- launch ----------------
extern "C" void kernel_launch(void* const* d_in, const int* in_sizes, int n_in,
                              void* d_out, int out_size, void* d_ws, size_t ws_size,
                              hipStream_t stream) {
  const float* x      = (const float*)d_in[0];
  const float* ve     = (const float*)d_in[1];
  const float* lam    = (const float*)d_in[2];
  const float* qkv_w  = (const float*)d_in[3];
  const float* proj_w = (const float*)d_in[4];
  float* out = (float*)d_out;

  char* p = (char*)d_ws;
  float* cosT = (float*)p;            p += (size_t)T_SEQ * 64 * 4;
  float* sinT = (float*)p;            p += (size_t)T_SEQ * 64 * 4;
  unsigned short* xb   = (unsigned short*)p; p += (size_t)T_SEQ * DIM * 2;
  unsigned short* wqb  = (unsigned short*)p; p += (size_t)3 * HDIM * DIM * 2;
  unsigned short* pwb  = (unsigned short*)p; p += (size_t)DIM * HDIM * 2;
  unsigned short* qkvb = (unsigned short*)p; p += (size_t)3 * NH * T_SEQ * HD * 2;
  unsigned short* vtb  = (unsigned short*)p; p += (size_t)NH * HD * T_SEQ * 2;
  unsigned short* aob  = (unsigned short*)p; p += (size_t)T_SEQ * HDIM * 2;
  unsigned char*  qk8  = (unsigned char*)p;  p += (size_t)2 * NH * T_SEQ * HD;

  // fused prep: x/qkv_w/proj_w converts + rope tables (boundaries 256-aligned)
  constexpr int PREP_N = T_SEQ * DIM / 4 + 3 * HDIM * DIM / 4 + DIM * HDIM / 4 + T_SEQ * 64;
  prep_all<<<PREP_N / 256, 256, 0, stream>>>(x, qkv_w, proj_w, xb, wqb, pwb, cosT, sinT);

  // QKV: 768 blocks = 3/CU exactly (R16 barrier-minimal BK=64 kernel)
  gemm256<0><<<768, 512, 0, stream>>>(xb, wqb, DIM, qkvb, nullptr, 3 * HDIM);
  // fused norm+rope->fp8 (8192 blocks) + vmix-transpose (2048 blocks)
  norm_vmix<<<10240, 256, 0, stream>>>(qkvb, cosT, sinT, ve, lam, vtb, qk8);
  attn_fwd<<<256, 512, 0, stream>>>(qk8, qk8 + (size_t)NH * T_SEQ * HD, vtb, aob);
  // proj: 256 blocks = 1/CU exactly
  gemm256<1><<<256, 512, 0, stream>>>(aob, pwb, HDIM, nullptr, out, HDIM);
}